// Round 3
// baseline (79343.475 us; speedup 1.0000x reference)
//
#include <hip/hip_runtime.h>
#include <math.h>

typedef unsigned short u16;
typedef __attribute__((ext_vector_type(8))) short short8;
typedef __attribute__((ext_vector_type(4))) float float4v;

#define HH   512
#define BB   256
#define TLEN 512
#define DD   64

__device__ __forceinline__ float sigm(float x) { return 1.0f / (1.0f + __expf(-x)); }
__device__ __forceinline__ float tanh_fast(float x) { return 2.0f * sigm(2.0f * x) - 1.0f; }

__device__ __forceinline__ u16 bf16rn(float v) {
    unsigned u = __float_as_uint(v);
    u += 0x7fffu + ((u >> 16) & 1u);
    return (u16)(u >> 16);
}
__device__ __forceinline__ float bf16tf(u16 h) { return __uint_as_float(((unsigned)h) << 16); }

// ---------------- precompute kernels ----------------

__global__ __launch_bounds__(256) void split_kernel(const float* __restrict__ src,
                                                    u16* __restrict__ hi, u16* __restrict__ lo, int n)
{
    for (int i = blockIdx.x * 256 + threadIdx.x; i < n; i += gridDim.x * 256) {
        float v = src[i];
        u16 h = bf16rn(v);
        hi[i] = h;
        lo[i] = bf16rn(v - bf16tf(h));
    }
}

__global__ __launch_bounds__(256) void zero_kernel(unsigned* p, int n)
{
    int i = blockIdx.x * 256 + threadIdx.x;
    if (i < n) p[i] = 0u;
}

// ---------------- device-wide barrier (sense via generation counter) ----------------

__device__ __forceinline__ void gridbar(unsigned* cnt, unsigned* gen)
{
    __syncthreads();
    __threadfence();   // release: flush h/c stores to coherence point
    if (threadIdx.x == 0) {
        unsigned g = __hip_atomic_load(gen, __ATOMIC_RELAXED, __HIP_MEMORY_SCOPE_AGENT);
        unsigned prev = __hip_atomic_fetch_add(cnt, 1u, __ATOMIC_ACQ_REL, __HIP_MEMORY_SCOPE_AGENT);
        if (prev == 255u) {
            __hip_atomic_store(cnt, 0u, __ATOMIC_RELAXED, __HIP_MEMORY_SCOPE_AGENT);
            __hip_atomic_store(gen, g + 1u, __ATOMIC_RELEASE, __HIP_MEMORY_SCOPE_AGENT);
        } else {
            while (__hip_atomic_load(gen, __ATOMIC_ACQUIRE, __HIP_MEMORY_SCOPE_AGENT) == g)
                __builtin_amdgcn_s_sleep(2);
        }
    }
    __syncthreads();
    __threadfence();   // acquire: invalidate stale cached h before reading
}

// ---------------- per-wave LSTM step (B held in registers) ----------------
// ROLE 0: layer0 (C=18 chunks: 2 of x[K=64] + 16 of h0[K=512])
// ROLE 1: layer1 (C=32 chunks: 16 of h0 + 16 of h1)
template <int ROLE>
__device__ __forceinline__ void lstm_wave_step(
    const u16* __restrict__ a1h, const u16* __restrict__ a1l,   // ROLE0: x base (incl. t*DD col offset); ROLE1: h0
    const u16* __restrict__ a2h, const u16* __restrict__ a2l,   // h(own layer) prev
    u16* __restrict__ wrh, u16* __restrict__ wrl,               // h write (hi/lo)
    float* __restrict__ cc, float* __restrict__ h1last, bool wlast,
    const short8 (&Bh)[32], const short8 (&Bl)[32],
    const int (&arow)[4], int lane, int wv, int jg,
    const float (&bias4)[4], int m0,
    float (*sEp)[4][16][17])
{
    constexpr int C  = ROLE ? 32 : 18;
    constexpr int C1 = ROLE ? 16 : 2;
    constexpr size_t LD1 = ROLE ? (size_t)HH : (size_t)(TLEN * DD);
    const int kq = (lane >> 4) * 8;

    auto ah_addr = [&](int c, int mt) -> const u16* {
        return (c < C1) ? (a1h + (size_t)arow[mt] * LD1 + (size_t)c * 32 + kq)
                        : (a2h + (size_t)arow[mt] * HH + (size_t)(c - C1) * 32 + kq);
    };
    auto al_addr = [&](int c, int mt) -> const u16* {
        return (c < C1) ? (a1l + (size_t)arow[mt] * LD1 + (size_t)c * 32 + kq)
                        : (a2l + (size_t)arow[mt] * HH + (size_t)(c - C1) * 32 + kq);
    };

    float4v acc[4];
#pragma unroll
    for (int mt = 0; mt < 4; ++mt) { acc[mt][0] = 0.f; acc[mt][1] = 0.f; acc[mt][2] = 0.f; acc[mt][3] = 0.f; }

    short8 Ah[2][4], Al[2][4];
#pragma unroll
    for (int p = 0; p < 2; ++p)
#pragma unroll
        for (int mt = 0; mt < 4; ++mt) {
            Ah[p][mt] = *(const short8*)ah_addr(p, mt);
            Al[p][mt] = *(const short8*)al_addr(p, mt);
        }

#pragma unroll
    for (int c = 0; c < C; ++c) {
        const int s = c & 1;
#pragma unroll
        for (int mt = 0; mt < 4; ++mt) {
            acc[mt] = __builtin_amdgcn_mfma_f32_16x16x32_bf16(Ah[s][mt], Bh[c], acc[mt], 0, 0, 0);
            acc[mt] = __builtin_amdgcn_mfma_f32_16x16x32_bf16(Ah[s][mt], Bl[c], acc[mt], 0, 0, 0);
            acc[mt] = __builtin_amdgcn_mfma_f32_16x16x32_bf16(Al[s][mt], Bh[c], acc[mt], 0, 0, 0);
        }
        if (c + 2 < C) {
#pragma unroll
            for (int mt = 0; mt < 4; ++mt) {
                Ah[s][mt] = *(const short8*)ah_addr(c + 2, mt);
                Al[s][mt] = *(const short8*)al_addr(c + 2, mt);
            }
        }
    }

    // stage acc to this wave's LDS region: [mt][row][col], col = gate*4 + jl
    const int rbase = (lane >> 4) * 4;
    const int nsel = lane & 15;
#pragma unroll
    for (int mt = 0; mt < 4; ++mt)
#pragma unroll
        for (int r = 0; r < 4; ++r)
            sEp[wv][mt][rbase + r][nsel] = acc[mt][r];

    // epilogue: lane handles (row = lane>>2, jl = lane&3), one unit per mt
    const int erow = lane >> 2;
    const int ejl = lane & 3;
#pragma unroll
    for (int mt = 0; mt < 4; ++mt) {
        float gi = sEp[wv][mt][erow][0 * 4 + ejl] + bias4[0];
        float gf = sEp[wv][mt][erow][1 * 4 + ejl] + bias4[1];
        float gG = sEp[wv][mt][erow][2 * 4 + ejl] + bias4[2];
        float go = sEp[wv][mt][erow][3 * 4 + ejl] + bias4[3];
        const int m = m0 + mt * 16 + erow;
        const size_t off = (size_t)m * HH + jg;
        float cp = cc[off];
        float cn = sigm(gf) * cp + sigm(gi) * tanh_fast(gG);
        float h  = sigm(go) * tanh_fast(cn);
        cc[off] = cn;
        u16 hv = bf16rn(h);
        wrh[off] = hv;
        wrl[off] = bf16rn(h - bf16tf(hv));
        if (ROLE == 1 && wlast) h1last[off] = h;
    }
}

// ---------------- persistent kernel: all 512 steps, both layers ----------------

__global__ __launch_bounds__(256, 1) void lstm_persist(
    const u16* __restrict__ xhi, const u16* __restrict__ xlo,
    const u16* __restrict__ wih0h, const u16* __restrict__ wih0l,
    const u16* __restrict__ whh0h, const u16* __restrict__ whh0l,
    const u16* __restrict__ wih1h, const u16* __restrict__ wih1l,
    const u16* __restrict__ whh1h, const u16* __restrict__ whh1l,
    const float* __restrict__ bi0, const float* __restrict__ bh0,
    const float* __restrict__ bi1, const float* __restrict__ bh1,
    u16* h0hi0, u16* h0lo0, u16* h0hi1, u16* h0lo1,
    u16* h1hi0, u16* h1lo0, u16* h1hi1, u16* h1lo1,
    float* c0, float* c1, float* h1last, unsigned* bar)
{
    __shared__ float sEp[4][4][16][17];

    const int tid = threadIdx.x, lane = tid & 63, wv = tid >> 6;
    const bool role1 = (blockIdx.x >= 128);
    const int idx = blockIdx.x & 127;
    const int m0 = (idx & 3) * 64;
    const int j0 = (idx >> 2) * 16;
    const int nsel = lane & 15;
    const int kq = (lane >> 4) * 8;
    const int gg = nsel >> 2, jlB = nsel & 3;
    const size_t growB = (size_t)gg * HH + j0 + wv * 4 + jlB;

    // ---- load B fragments into registers (once) ----
    short8 Bh[32], Bl[32];
    if (!role1) {
#pragma unroll
        for (int c = 0; c < 2; ++c) {
            Bh[c] = *(const short8*)(wih0h + growB * DD + c * 32 + kq);
            Bl[c] = *(const short8*)(wih0l + growB * DD + c * 32 + kq);
        }
#pragma unroll
        for (int c = 0; c < 16; ++c) {
            Bh[2 + c] = *(const short8*)(whh0h + growB * HH + c * 32 + kq);
            Bl[2 + c] = *(const short8*)(whh0l + growB * HH + c * 32 + kq);
        }
#pragma unroll
        for (int c = 18; c < 32; ++c) { Bh[c] = Bh[0]; Bl[c] = Bl[0]; } // init unused
    } else {
#pragma unroll
        for (int c = 0; c < 16; ++c) {
            Bh[c] = *(const short8*)(wih1h + growB * HH + c * 32 + kq);
            Bl[c] = *(const short8*)(wih1l + growB * HH + c * 32 + kq);
            Bh[16 + c] = *(const short8*)(whh1h + growB * HH + c * 32 + kq);
            Bl[16 + c] = *(const short8*)(whh1l + growB * HH + c * 32 + kq);
        }
    }

    const float* pbi = role1 ? bi1 : bi0;
    const float* pbh = role1 ? bh1 : bh0;
    const int jg = j0 + wv * 4 + (lane & 3);
    float bias4[4];
#pragma unroll
    for (int q = 0; q < 4; ++q) bias4[q] = pbi[q * HH + jg] + pbh[q * HH + jg];
    float* cc = role1 ? c1 : c0;

    int arow[4];
#pragma unroll
    for (int mt = 0; mt < 4; ++mt) arow[mt] = m0 + mt * 16 + nsel;

    unsigned* cnt = bar;
    unsigned* gen = bar + 1;

    for (int it = 0; it <= TLEN; ++it) {
        const int rb = it & 1;
        if (!role1) {
            if (it < TLEN) {
                const u16* a2h = rb ? h0hi1 : h0hi0;
                const u16* a2l = rb ? h0lo1 : h0lo0;
                u16* wrh = rb ? h0hi0 : h0hi1;
                u16* wrl = rb ? h0lo0 : h0lo1;
                lstm_wave_step<0>(xhi + (size_t)it * DD, xlo + (size_t)it * DD,
                                  a2h, a2l, wrh, wrl, cc, h1last, false,
                                  Bh, Bl, arow, lane, wv, jg, bias4, m0, sEp);
            }
        } else {
            if (it > 0) {
                const u16* a1h = rb ? h0hi1 : h0hi0;
                const u16* a1l = rb ? h0lo1 : h0lo0;
                const u16* a2h = rb ? h1hi1 : h1hi0;
                const u16* a2l = rb ? h1lo1 : h1lo0;
                u16* wrh = rb ? h1hi0 : h1hi1;
                u16* wrl = rb ? h1lo0 : h1lo1;
                lstm_wave_step<1>(a1h, a1l, a2h, a2l, wrh, wrl, cc, h1last, it == TLEN,
                                  Bh, Bl, arow, lane, wv, jg, bias4, m0, sEp);
            }
        }
        if (it < TLEN) gridbar(cnt, gen);
    }
}

// ---------------- FC head (proven) ----------------

template <int MODE>
__global__ __launch_bounds__(256) void gemm_step(
    const float* __restrict__ A1, int lda1, int K1, const float* __restrict__ W1,
    const float* __restrict__ A2, int K2, const float* __restrict__ W2,
    const float* __restrict__ b1, const float* __restrict__ b2,
    const float* __restrict__ c_in, float* __restrict__ c_out,
    float* __restrict__ h_out)
{
    __shared__ float sA[16][33];
    __shared__ float sW[128][33];

    const int tid = threadIdx.x;
    const int tj  = tid & 31;
    const int tg  = tid >> 5;
    const int m0  = blockIdx.x * 16;
    const int j0  = blockIdx.y * ((MODE == 0) ? 32 : 128);

    float acc[2][4] = {{0.f, 0.f, 0.f, 0.f}, {0.f, 0.f, 0.f, 0.f}};

    for (int seg = 0; seg < 2; ++seg) {
        const float* A  = seg ? A2 : A1;
        const float* W  = seg ? W2 : W1;
        const int    K  = seg ? K2 : K1;
        const int    ld = seg ? HH : lda1;
        if (K == 0) continue;
        for (int kb = 0; kb < K; kb += 32) {
            __syncthreads();
            {
                int idxq = tid;
#pragma unroll
                for (int r = 0; r < 2; ++r, idxq += 256) {
                    int row = idxq >> 5, col = idxq & 31;
                    sA[row][col] = A[(m0 + row) * ld + kb + col];
                }
            }
            {
#pragma unroll
                for (int i = 0; i < 16; ++i) {
                    int idxq = i * 256 + tid;
                    int row = idxq >> 5, col = idxq & 31;
                    int grw;
                    if (MODE == 0) grw = (row >> 5) * HH + j0 + (row & 31);
                    else           grw = j0 + row;
                    sW[row][col] = W[grw * K + kb + col];
                }
            }
            __syncthreads();
#pragma unroll
            for (int k = 0; k < 32; ++k) {
                float a0 = sA[tg][k];
                float a1 = sA[tg + 8][k];
                float w0 = sW[tj][k];
                float w1 = sW[32 + tj][k];
                float w2 = sW[64 + tj][k];
                float w3 = sW[96 + tj][k];
                acc[0][0] += a0 * w0; acc[0][1] += a0 * w1;
                acc[0][2] += a0 * w2; acc[0][3] += a0 * w3;
                acc[1][0] += a1 * w0; acc[1][1] += a1 * w1;
                acc[1][2] += a1 * w2; acc[1][3] += a1 * w3;
            }
        }
    }

    if (MODE == 0) {
        const int j = j0 + tj;
        const float bi = b1[j] + b2[j];
        const float bf = b1[HH + j] + b2[HH + j];
        const float bg = b1[2 * HH + j] + b2[2 * HH + j];
        const float bo = b1[3 * HH + j] + b2[3 * HH + j];
#pragma unroll
        for (int r = 0; r < 2; ++r) {
            int m = m0 + tg + r * 8;
            float gi = acc[r][0] + bi;
            float gf = acc[r][1] + bf;
            float gg = acc[r][2] + bg;
            float go = acc[r][3] + bo;
            float cp = c_in[m * HH + j];
            float c  = sigm(gf) * cp + sigm(gi) * tanhf(gg);
            float h  = sigm(go) * tanhf(c);
            c_out[m * HH + j] = c;
            h_out[m * HH + j] = h;
        }
    } else {
#pragma unroll
        for (int r = 0; r < 2; ++r) {
            int m = m0 + tg + r * 8;
#pragma unroll
            for (int q = 0; q < 4; ++q) {
                int nn = j0 + q * 32 + tj;
                float v = acc[r][q] + b1[nn];
                h_out[m * HH + nn] = fmaxf(v, 0.f);
            }
        }
    }
}

__global__ __launch_bounds__(64) void fc2_kernel(
    const float* __restrict__ z, const float* __restrict__ W,
    const float* __restrict__ b, float* __restrict__ out)
{
    int m = blockIdx.x;
    int lane = threadIdx.x;
    float zr[8];
#pragma unroll
    for (int u = 0; u < 8; ++u) zr[u] = z[m * 512 + u * 64 + lane];
#pragma unroll
    for (int o = 0; o < 8; ++o) {
        float s = 0.f;
#pragma unroll
        for (int u = 0; u < 8; ++u) s += zr[u] * W[o * 512 + u * 64 + lane];
#pragma unroll
        for (int off = 32; off > 0; off >>= 1) s += __shfl_down(s, off);
        if (lane == 0) out[m * 8 + o] = s + b[o];
    }
}

__global__ __launch_bounds__(256) void zero_f_kernel(float* p, int n)
{
    int i = blockIdx.x * 256 + threadIdx.x;
    if (i < n) p[i] = 0.f;
}

// ---------------- host ----------------

extern "C" void kernel_launch(void* const* d_in, const int* in_sizes, int n_in,
                              void* d_out, int out_size, void* d_ws, size_t ws_size,
                              hipStream_t stream)
{
    const float* x     = (const float*)d_in[0];
    const float* W_ih0 = (const float*)d_in[1];
    const float* W_hh0 = (const float*)d_in[2];
    const float* b_ih0 = (const float*)d_in[3];
    const float* b_hh0 = (const float*)d_in[4];
    const float* W_ih1 = (const float*)d_in[5];
    const float* W_hh1 = (const float*)d_in[6];
    const float* b_ih1 = (const float*)d_in[7];
    const float* b_hh1 = (const float*)d_in[8];
    const float* W_fc1 = (const float*)d_in[9];
    const float* b_fc1 = (const float*)d_in[10];
    const float* W_fc2 = (const float*)d_in[11];
    const float* b_fc2 = (const float*)d_in[12];
    float* out = (float*)d_out;

    const size_t S  = (size_t)BB * HH;        // 131072 elems
    const size_t SB = S * sizeof(u16);        // 262144 B
    const size_t SF = S * sizeof(float);      // 524288 B
    const size_t XN = (size_t)BB * TLEN * DD; // 8388608 elems

    const size_t NEED = 256 + 8 * SB + 4 * SF + 2 * XN * 2 +
                        2 * 131072 * 2 + 6 * 1048576 * 2;

    if (ws_size >= NEED) {
        char* W = (char*)d_ws;
        size_t o = 0;
        // ---- zero region (bar + initial-state buffers + c) ----
        unsigned* bar = (unsigned*)(W + o); o += 256;
        u16* h0hi0 = (u16*)(W + o); o += SB;
        u16* h0lo0 = (u16*)(W + o); o += SB;
        u16* h1hi1 = (u16*)(W + o); o += SB;
        u16* h1lo1 = (u16*)(W + o); o += SB;
        float* c0 = (float*)(W + o); o += SF;
        float* c1 = (float*)(W + o); o += SF;
        const size_t ZBYTES = o; // 2097408
        // ---- rest ----
        u16* h0hi1 = (u16*)(W + o); o += SB;
        u16* h0lo1 = (u16*)(W + o); o += SB;
        u16* h1hi0 = (u16*)(W + o); o += SB;
        u16* h1lo0 = (u16*)(W + o); o += SB;
        float* h1last = (float*)(W + o); o += SF;
        float* zfc    = (float*)(W + o); o += SF;
        u16* xhi = (u16*)(W + o); o += XN * 2;
        u16* xlo = (u16*)(W + o); o += XN * 2;
        u16* wih0h = (u16*)(W + o); o += 131072 * 2;
        u16* wih0l = (u16*)(W + o); o += 131072 * 2;
        u16* whh0h = (u16*)(W + o); o += 1048576 * 2;
        u16* whh0l = (u16*)(W + o); o += 1048576 * 2;
        u16* wih1h = (u16*)(W + o); o += 1048576 * 2;
        u16* wih1l = (u16*)(W + o); o += 1048576 * 2;
        u16* whh1h = (u16*)(W + o); o += 1048576 * 2;
        u16* whh1l = (u16*)(W + o); o += 1048576 * 2;

        zero_kernel<<<(int)((ZBYTES / 4 + 255) / 256), 256, 0, stream>>>((unsigned*)d_ws, (int)(ZBYTES / 4));
        split_kernel<<<2048, 256, 0, stream>>>(x, xhi, xlo, (int)XN);
        split_kernel<<<512, 256, 0, stream>>>(W_ih0, wih0h, wih0l, 131072);
        split_kernel<<<2048, 256, 0, stream>>>(W_hh0, whh0h, whh0l, 1048576);
        split_kernel<<<2048, 256, 0, stream>>>(W_ih1, wih1h, wih1l, 1048576);
        split_kernel<<<2048, 256, 0, stream>>>(W_hh1, whh1h, whh1l, 1048576);

        lstm_persist<<<256, 256, 0, stream>>>(
            xhi, xlo,
            wih0h, wih0l, whh0h, whh0l,
            wih1h, wih1l, whh1h, whh1l,
            b_ih0, b_hh0, b_ih1, b_hh1,
            h0hi0, h0lo0, h0hi1, h0lo1,
            h1hi0, h1lo0, h1hi1, h1lo1,
            c0, c1, h1last, bar);

        dim3 grid_fc1(BB / 16, 512 / 128);
        gemm_step<1><<<grid_fc1, 256, 0, stream>>>(
            h1last, HH, HH, W_fc1, nullptr, 0, nullptr,
            b_fc1, nullptr, nullptr, nullptr, zfc);
        fc2_kernel<<<BB, 64, 0, stream>>>(zfc, W_fc2, b_fc2, out);
        return;
    }

    // -------- fallback: fp32 path (needs ~3.7 MB ws) --------
    float* wsf = (float*)d_ws;
    float* h0a = wsf + 0 * S;
    float* c0  = wsf + 1 * S;
    float* h1a = wsf + 2 * S;
    float* c1  = wsf + 3 * S;
    float* h0b = wsf + 4 * S;
    float* h1b = wsf + 5 * S;
    float* zb  = wsf + 6 * S;
    float* h0buf[2] = {h0a, h0b};
    float* h1buf[2] = {h1a, h1b};

    zero_f_kernel<<<(int)((4 * S + 255) / 256), 256, 0, stream>>>(wsf, (int)(4 * S));

    dim3 grid_lstm(BB / 16, HH / 32);
    for (int t = 0; t < TLEN; ++t) {
        const float* xt = x + (size_t)t * DD;
        gemm_step<0><<<grid_lstm, 256, 0, stream>>>(
            xt, TLEN * DD, DD, W_ih0,
            h0buf[t & 1], HH, W_hh0,
            b_ih0, b_hh0, c0, c0, h0buf[(t + 1) & 1]);
        gemm_step<0><<<grid_lstm, 256, 0, stream>>>(
            h0buf[(t + 1) & 1], HH, HH, W_ih1,
            h1buf[t & 1], HH, W_hh1,
            b_ih1, b_hh1, c1, c1, h1buf[(t + 1) & 1]);
    }
    dim3 grid_fc1(BB / 16, 512 / 128);
    gemm_step<1><<<grid_fc1, 256, 0, stream>>>(
        h1buf[0], HH, HH, W_fc1, nullptr, 0, nullptr,
        b_fc1, nullptr, nullptr, nullptr, zb);
    fc2_kernel<<<BB, 64, 0, stream>>>(zb, W_fc2, b_fc2, out);
}

// Round 4
// 22218.913 us; speedup vs baseline: 3.5710x; 3.5710x over previous
//
#include <hip/hip_runtime.h>
#include <math.h>

typedef unsigned short u16;
typedef __attribute__((ext_vector_type(8))) short short8;
typedef __attribute__((ext_vector_type(4))) float float4v;

#define HH   512
#define BB   256
#define TLEN 512
#define DD   64

__device__ __forceinline__ float sigm(float x) { return 1.0f / (1.0f + __expf(-x)); }

__device__ __forceinline__ u16 bf16rn(float v) {
    unsigned u = __float_as_uint(v);
    u += 0x7fffu + ((u >> 16) & 1u);
    return (u16)(u >> 16);
}
__device__ __forceinline__ float bf16tf(u16 h) { return __uint_as_float(((unsigned)h) << 16); }

// ---------------- precompute kernels ----------------

__global__ __launch_bounds__(256) void split_kernel(const float* __restrict__ src,
                                                    u16* __restrict__ hi, u16* __restrict__ lo, int n)
{
    for (int i = blockIdx.x * 256 + threadIdx.x; i < n; i += gridDim.x * 256) {
        float v = src[i];
        u16 h = bf16rn(v);
        hi[i] = h;
        lo[i] = bf16rn(v - bf16tf(h));
    }
}

__global__ __launch_bounds__(256) void zero_kernel(unsigned* p, int n)
{
    int i = blockIdx.x * 256 + threadIdx.x;
    if (i < n) p[i] = 0u;
}

// ---------------- split-K chunk loop (B in registers, depth-2 A prefetch) ----------------

__device__ __forceinline__ float4v mfma16(short8 a, short8 b, float4v c) {
    return __builtin_amdgcn_mfma_f32_16x16x32_bf16(a, b, c, 0, 0, 0);
}

template <int NC, int NX>
__device__ __forceinline__ void chunk_loop(
    const u16* __restrict__ xh, const u16* __restrict__ xl, size_t ldx,  // first NX chunks (x input)
    const u16* __restrict__ hh, const u16* __restrict__ hl, int koff,    // remaining chunks (stride HH)
    const short8 (&Bh)[16], const short8 (&Bl)[16],
    const int (&arow)[4], int kq, float4v (&acc)[4])
{
    auto ha = [&](int c, int mt) -> const u16* {
        return (c < NX) ? (xh + (size_t)arow[mt] * ldx + (size_t)c * 32 + kq)
                        : (hh + (size_t)arow[mt] * HH + (size_t)(koff + c - NX) * 32 + kq);
    };
    auto la = [&](int c, int mt) -> const u16* {
        return (c < NX) ? (xl + (size_t)arow[mt] * ldx + (size_t)c * 32 + kq)
                        : (hl + (size_t)arow[mt] * HH + (size_t)(koff + c - NX) * 32 + kq);
    };
    short8 Ah[2][4], Al[2][4];
#pragma unroll
    for (int p = 0; p < 2 && p < NC; ++p)
#pragma unroll
        for (int mt = 0; mt < 4; ++mt) {
            Ah[p][mt] = *(const short8*)ha(p, mt);
            Al[p][mt] = *(const short8*)la(p, mt);
        }
#pragma unroll
    for (int c = 0; c < NC; ++c) {
        const int s = c & 1;
#pragma unroll
        for (int mt = 0; mt < 4; ++mt) {
            acc[mt] = mfma16(Ah[s][mt], Bh[c], acc[mt]);
            acc[mt] = mfma16(Ah[s][mt], Bl[c], acc[mt]);
            acc[mt] = mfma16(Al[s][mt], Bh[c], acc[mt]);
        }
        if (c + 2 < NC) {
#pragma unroll
            for (int mt = 0; mt < 4; ++mt) {
                Ah[s][mt] = *(const short8*)ha(c + 2, mt);
                Al[s][mt] = *(const short8*)la(c + 2, mt);
            }
        }
    }
}

// ---------------- grid barrier: distributed flags, relaxed polling ----------------
// flags[i*16] holds the step number block i has completed. gen = flags[4096].

__device__ __forceinline__ void gridbar(unsigned* flags, unsigned* gen,
                                        unsigned it, int tid, int bid)
{
    __syncthreads();                       // all waves done (stores drained to L2)
    if (tid == 0) {
        __threadfence();                   // push this block's h stores L2 -> LLC
        __hip_atomic_store(&flags[bid * 16], it + 1, __ATOMIC_RELEASE, __HIP_MEMORY_SCOPE_AGENT);
    }
    if (bid == 0) {
        if (tid < 256) {
            while (__hip_atomic_load(&flags[tid * 16], __ATOMIC_RELAXED, __HIP_MEMORY_SCOPE_AGENT) < it + 1)
                __builtin_amdgcn_s_sleep(1);
        }
        __syncthreads();
        if (tid == 0)
            __hip_atomic_store(gen, it + 1, __ATOMIC_RELEASE, __HIP_MEMORY_SCOPE_AGENT);
    }
    if (tid == 0) {
        while (__hip_atomic_load(gen, __ATOMIC_RELAXED, __HIP_MEMORY_SCOPE_AGENT) < it + 1)
            __builtin_amdgcn_s_sleep(1);
        __threadfence();                   // invalidate stale L1/L2 before reading others' h
    }
    __syncthreads();
}

// ---------------- persistent kernel ----------------
// 256 blocks x 512 threads (8 waves = 4 j-subslices x 2 K-halves), 1 block/CU.
// blocks 0..127: layer0 step t=it (skip it==512); 128..255: layer1 step t=it-1 (skip it==0).
// Block tile: 64 m-rows x 16 h-units. Wave: 4 m-tiles x 16 n (4 gates x 4 j), half of K.
// Weights live in VGPRs for the whole sequence; c lives in thread registers.

__global__ __launch_bounds__(512, 2) void lstm_persist(
    const u16* __restrict__ xhi, const u16* __restrict__ xlo,
    const u16* __restrict__ wih0h, const u16* __restrict__ wih0l,
    const u16* __restrict__ whh0h, const u16* __restrict__ whh0l,
    const u16* __restrict__ wih1h, const u16* __restrict__ wih1l,
    const u16* __restrict__ whh1h, const u16* __restrict__ whh1l,
    const float* __restrict__ bi0, const float* __restrict__ bh0,
    const float* __restrict__ bi1, const float* __restrict__ bh1,
    u16* h0hi0, u16* h0lo0, u16* h0hi1, u16* h0lo1,
    u16* h1hi0, u16* h1lo0, u16* h1hi1, u16* h1lo1,
    float* h1last, unsigned* flags)
{
    __shared__ float sEp[8][4][16][20];    // [wave][mt][row][n(pad 20)]

    const int tid  = threadIdx.x;
    const int lane = tid & 63;
    const int wv   = tid >> 6;             // 0..7
    const int ksel = wv & 1;               // K-half
    const int jsub = wv >> 1;              // j subslice (4 j each)
    const int bid  = blockIdx.x;
    const bool role1 = (bid >= 128);
    const int idx = bid & 127;
    const int m0  = (idx & 3) * 64;
    const int j0  = (idx >> 2) * 16;
    const int nsel = lane & 15;
    const int kq   = (lane >> 4) * 8;
    unsigned* gen = flags + 4096;

    // ---- B fragments -> registers, once. n = gate*4 + jl ----
    const size_t growB = (size_t)(nsel >> 2) * HH + j0 + jsub * 4 + (nsel & 3);
    short8 Bh[16], Bl[16];
    if (!role1) {
        if (ksel == 0) {
#pragma unroll
            for (int c = 0; c < 2; ++c) {
                Bh[c] = *(const short8*)(wih0h + growB * DD + c * 32 + kq);
                Bl[c] = *(const short8*)(wih0l + growB * DD + c * 32 + kq);
            }
#pragma unroll
            for (int c = 0; c < 8; ++c) {
                Bh[2 + c] = *(const short8*)(whh0h + growB * HH + c * 32 + kq);
                Bl[2 + c] = *(const short8*)(whh0l + growB * HH + c * 32 + kq);
            }
        } else {
#pragma unroll
            for (int c = 0; c < 8; ++c) {
                Bh[c] = *(const short8*)(whh0h + growB * HH + (8 + c) * 32 + kq);
                Bl[c] = *(const short8*)(whh0l + growB * HH + (8 + c) * 32 + kq);
            }
        }
    } else {
        const u16* Wh = ksel ? whh1h : wih1h;
        const u16* Wl = ksel ? whh1l : wih1l;
#pragma unroll
        for (int c = 0; c < 16; ++c) {
            Bh[c] = *(const short8*)(Wh + growB * HH + c * 32 + kq);
            Bl[c] = *(const short8*)(Wl + growB * HH + c * 32 + kq);
        }
    }

    int arow[4];
#pragma unroll
    for (int mt = 0; mt < 4; ++mt) arow[mt] = m0 + mt * 16 + nsel;

    // ---- epilogue constants: thread -> (j, rows mlA and mlA+32) ----
    const int jl16 = tid & 15;
    const int mlA  = tid >> 4;             // 0..31
    const int jglob = j0 + jl16;
    const float* pbi = role1 ? bi1 : bi0;
    const float* pbh = role1 ? bh1 : bh0;
    float bias4[4];
#pragma unroll
    for (int q = 0; q < 4; ++q) bias4[q] = pbi[q * HH + jglob] + pbh[q * HH + jglob];
    const int ejs = jl16 >> 2, ejl = jl16 & 3;

    float creg[2] = {0.f, 0.f};            // persistent c state

    for (int it = 0; it <= TLEN; ++it) {
        const int rb = it & 1;
        const bool active = role1 ? (it > 0) : (it < TLEN);
        if (active) {
            const u16* h0rh = rb ? h0hi1 : h0hi0;
            const u16* h0rl = rb ? h0lo1 : h0lo0;
            float4v acc[4];
#pragma unroll
            for (int mt = 0; mt < 4; ++mt) { acc[mt][0]=0.f; acc[mt][1]=0.f; acc[mt][2]=0.f; acc[mt][3]=0.f; }

            if (!role1) {
                const u16* xb  = xhi + (size_t)it * DD;
                const u16* xbl = xlo + (size_t)it * DD;
                if (ksel == 0)
                    chunk_loop<10, 2>(xb, xbl, (size_t)TLEN * DD, h0rh, h0rl, 0, Bh, Bl, arow, kq, acc);
                else
                    chunk_loop<8, 0>(nullptr, nullptr, 0, h0rh, h0rl, 8, Bh, Bl, arow, kq, acc);
            } else {
                if (ksel == 0) {
                    chunk_loop<16, 0>(nullptr, nullptr, 0, h0rh, h0rl, 0, Bh, Bl, arow, kq, acc);
                } else {
                    const u16* h1rh = rb ? h1hi1 : h1hi0;
                    const u16* h1rl = rb ? h1lo1 : h1lo0;
                    chunk_loop<16, 0>(nullptr, nullptr, 0, h1rh, h1rl, 0, Bh, Bl, arow, kq, acc);
                }
            }

            // stage partial acc: sEp[wv][mt][row][n]
#pragma unroll
            for (int mt = 0; mt < 4; ++mt)
#pragma unroll
                for (int r = 0; r < 4; ++r)
                    sEp[wv][mt][(lane >> 4) * 4 + r][nsel] = acc[mt][r];
            __syncthreads();

            // epilogue: combine K-halves, gate math, h hi/lo store; c stays in regs
            u16* wrh;
            u16* wrl;
            if (!role1) { wrh = rb ? h0hi0 : h0hi1; wrl = rb ? h0lo0 : h0lo1; }
            else        { wrh = rb ? h1hi0 : h1hi1; wrl = rb ? h1lo0 : h1lo1; }
#pragma unroll
            for (int e = 0; e < 2; ++e) {
                const int ml = mlA + e * 32;
                const int mt = ml >> 4, row = ml & 15;
                float g[4];
#pragma unroll
                for (int q = 0; q < 4; ++q)
                    g[q] = sEp[ejs * 2 + 0][mt][row][q * 4 + ejl]
                         + sEp[ejs * 2 + 1][mt][row][q * 4 + ejl] + bias4[q];
                float cn = sigm(g[1]) * creg[e] + sigm(g[0]) * tanhf(g[2]);
                float h  = sigm(g[3]) * tanhf(cn);
                creg[e] = cn;
                const size_t off = (size_t)(m0 + ml) * HH + jglob;
                u16 hv = bf16rn(h);
                wrh[off] = hv;
                wrl[off] = bf16rn(h - bf16tf(hv));
                if (role1 && it == TLEN) h1last[off] = h;
            }
        }
        if (it < TLEN) gridbar(flags, gen, (unsigned)it, tid, bid);
    }
}

// ---------------- FC head (proven) ----------------

template <int MODE>
__global__ __launch_bounds__(256) void gemm_step(
    const float* __restrict__ A1, int lda1, int K1, const float* __restrict__ W1,
    const float* __restrict__ A2, int K2, const float* __restrict__ W2,
    const float* __restrict__ b1, const float* __restrict__ b2,
    const float* __restrict__ c_in, float* __restrict__ c_out,
    float* __restrict__ h_out)
{
    __shared__ float sA[16][33];
    __shared__ float sW[128][33];

    const int tid = threadIdx.x;
    const int tj  = tid & 31;
    const int tg  = tid >> 5;
    const int m0  = blockIdx.x * 16;
    const int j0  = blockIdx.y * ((MODE == 0) ? 32 : 128);

    float acc[2][4] = {{0.f, 0.f, 0.f, 0.f}, {0.f, 0.f, 0.f, 0.f}};

    for (int seg = 0; seg < 2; ++seg) {
        const float* A  = seg ? A2 : A1;
        const float* W  = seg ? W2 : W1;
        const int    K  = seg ? K2 : K1;
        const int    ld = seg ? HH : lda1;
        if (K == 0) continue;
        for (int kb = 0; kb < K; kb += 32) {
            __syncthreads();
            {
                int idxq = tid;
#pragma unroll
                for (int r = 0; r < 2; ++r, idxq += 256) {
                    int row = idxq >> 5, col = idxq & 31;
                    sA[row][col] = A[(m0 + row) * ld + kb + col];
                }
            }
            {
#pragma unroll
                for (int i = 0; i < 16; ++i) {
                    int idxq = i * 256 + tid;
                    int row = idxq >> 5, col = idxq & 31;
                    int grw;
                    if (MODE == 0) grw = (row >> 5) * HH + j0 + (row & 31);
                    else           grw = j0 + row;
                    sW[row][col] = W[grw * K + kb + col];
                }
            }
            __syncthreads();
#pragma unroll
            for (int k = 0; k < 32; ++k) {
                float a0 = sA[tg][k];
                float a1 = sA[tg + 8][k];
                float w0 = sW[tj][k];
                float w1 = sW[32 + tj][k];
                float w2 = sW[64 + tj][k];
                float w3 = sW[96 + tj][k];
                acc[0][0] += a0 * w0; acc[0][1] += a0 * w1;
                acc[0][2] += a0 * w2; acc[0][3] += a0 * w3;
                acc[1][0] += a1 * w0; acc[1][1] += a1 * w1;
                acc[1][2] += a1 * w2; acc[1][3] += a1 * w3;
            }
        }
    }

    if (MODE == 1) {
#pragma unroll
        for (int r = 0; r < 2; ++r) {
            int m = m0 + tg + r * 8;
#pragma unroll
            for (int q = 0; q < 4; ++q) {
                int nn = j0 + q * 32 + tj;
                float v = acc[r][q] + b1[nn];
                h_out[m * HH + nn] = fmaxf(v, 0.f);
            }
        }
    }
}

__global__ __launch_bounds__(64) void fc2_kernel(
    const float* __restrict__ z, const float* __restrict__ W,
    const float* __restrict__ b, float* __restrict__ out)
{
    int m = blockIdx.x;
    int lane = threadIdx.x;
    float zr[8];
#pragma unroll
    for (int u = 0; u < 8; ++u) zr[u] = z[m * 512 + u * 64 + lane];
#pragma unroll
    for (int o = 0; o < 8; ++o) {
        float s = 0.f;
#pragma unroll
        for (int u = 0; u < 8; ++u) s += zr[u] * W[o * 512 + u * 64 + lane];
#pragma unroll
        for (int off = 32; off > 0; off >>= 1) s += __shfl_down(s, off);
        if (lane == 0) out[m * 8 + o] = s + b[o];
    }
}

__global__ __launch_bounds__(256) void zero_f_kernel(float* p, int n)
{
    int i = blockIdx.x * 256 + threadIdx.x;
    if (i < n) p[i] = 0.f;
}

// fp32 LSTM step for fallback path
__global__ __launch_bounds__(256) void gemm_lstm_f32(
    const float* __restrict__ A1, int lda1, int K1, const float* __restrict__ W1,
    const float* __restrict__ A2, int K2, const float* __restrict__ W2,
    const float* __restrict__ b1, const float* __restrict__ b2,
    const float* __restrict__ c_in, float* __restrict__ c_out,
    float* __restrict__ h_out)
{
    __shared__ float sA[16][33];
    __shared__ float sW[128][33];

    const int tid = threadIdx.x;
    const int tj  = tid & 31;
    const int tg  = tid >> 5;
    const int m0  = blockIdx.x * 16;
    const int j0  = blockIdx.y * 32;

    float acc[2][4] = {{0.f, 0.f, 0.f, 0.f}, {0.f, 0.f, 0.f, 0.f}};

    for (int seg = 0; seg < 2; ++seg) {
        const float* A  = seg ? A2 : A1;
        const float* W  = seg ? W2 : W1;
        const int    K  = seg ? K2 : K1;
        const int    ld = seg ? HH : lda1;
        for (int kb = 0; kb < K; kb += 32) {
            __syncthreads();
            {
                int idxq = tid;
#pragma unroll
                for (int r = 0; r < 2; ++r, idxq += 256) {
                    int row = idxq >> 5, col = idxq & 31;
                    sA[row][col] = A[(m0 + row) * ld + kb + col];
                }
            }
            {
#pragma unroll
                for (int i = 0; i < 16; ++i) {
                    int idxq = i * 256 + tid;
                    int row = idxq >> 5, col = idxq & 31;
                    int grw = (row >> 5) * HH + j0 + (row & 31);
                    sW[row][col] = W[grw * K + kb + col];
                }
            }
            __syncthreads();
#pragma unroll
            for (int k = 0; k < 32; ++k) {
                float a0 = sA[tg][k];
                float a1 = sA[tg + 8][k];
                float w0 = sW[tj][k];
                float w1 = sW[32 + tj][k];
                float w2 = sW[64 + tj][k];
                float w3 = sW[96 + tj][k];
                acc[0][0] += a0 * w0; acc[0][1] += a0 * w1;
                acc[0][2] += a0 * w2; acc[0][3] += a0 * w3;
                acc[1][0] += a1 * w0; acc[1][1] += a1 * w1;
                acc[1][2] += a1 * w2; acc[1][3] += a1 * w3;
            }
        }
    }

    const int j = j0 + tj;
    const float bi = b1[j] + b2[j];
    const float bf = b1[HH + j] + b2[HH + j];
    const float bg = b1[2 * HH + j] + b2[2 * HH + j];
    const float bo = b1[3 * HH + j] + b2[3 * HH + j];
#pragma unroll
    for (int r = 0; r < 2; ++r) {
        int m = m0 + tg + r * 8;
        float gi = acc[r][0] + bi;
        float gf = acc[r][1] + bf;
        float gg = acc[r][2] + bg;
        float go = acc[r][3] + bo;
        float cp = c_in[m * HH + j];
        float c  = sigm(gf) * cp + sigm(gi) * tanhf(gg);
        float h  = sigm(go) * tanhf(c);
        c_out[m * HH + j] = c;
        h_out[m * HH + j] = h;
    }
}

// ---------------- host ----------------

extern "C" void kernel_launch(void* const* d_in, const int* in_sizes, int n_in,
                              void* d_out, int out_size, void* d_ws, size_t ws_size,
                              hipStream_t stream)
{
    const float* x     = (const float*)d_in[0];
    const float* W_ih0 = (const float*)d_in[1];
    const float* W_hh0 = (const float*)d_in[2];
    const float* b_ih0 = (const float*)d_in[3];
    const float* b_hh0 = (const float*)d_in[4];
    const float* W_ih1 = (const float*)d_in[5];
    const float* W_hh1 = (const float*)d_in[6];
    const float* b_ih1 = (const float*)d_in[7];
    const float* b_hh1 = (const float*)d_in[8];
    const float* W_fc1 = (const float*)d_in[9];
    const float* b_fc1 = (const float*)d_in[10];
    const float* W_fc2 = (const float*)d_in[11];
    const float* b_fc2 = (const float*)d_in[12];
    float* out = (float*)d_out;

    const size_t S  = (size_t)BB * HH;        // 131072 elems
    const size_t SB = S * sizeof(u16);        // 262144 B
    const size_t SF = S * sizeof(float);      // 524288 B
    const size_t XN = (size_t)BB * TLEN * DD; // 8388608 elems
    const size_t FLAGB = (4096 + 16) * 4;     // flags[256*16] + gen line

    const size_t NEED = FLAGB + 8 * SB + 2 * SF + 2 * XN * 2 +
                        2 * 131072 * 2 + 6 * 1048576 * 2;

    if (ws_size >= NEED) {
        char* W = (char*)d_ws;
        size_t o = 0;
        // ---- zero region: flags + initial-state buffers ----
        unsigned* flags = (unsigned*)(W + o); o += FLAGB;
        u16* h0hi0 = (u16*)(W + o); o += SB;
        u16* h0lo0 = (u16*)(W + o); o += SB;
        u16* h1hi1 = (u16*)(W + o); o += SB;
        u16* h1lo1 = (u16*)(W + o); o += SB;
        const size_t ZBYTES = o;
        // ---- rest ----
        u16* h0hi1 = (u16*)(W + o); o += SB;
        u16* h0lo1 = (u16*)(W + o); o += SB;
        u16* h1hi0 = (u16*)(W + o); o += SB;
        u16* h1lo0 = (u16*)(W + o); o += SB;
        float* h1last = (float*)(W + o); o += SF;
        float* zfc    = (float*)(W + o); o += SF;
        u16* xhi = (u16*)(W + o); o += XN * 2;
        u16* xlo = (u16*)(W + o); o += XN * 2;
        u16* wih0h = (u16*)(W + o); o += 131072 * 2;
        u16* wih0l = (u16*)(W + o); o += 131072 * 2;
        u16* whh0h = (u16*)(W + o); o += 1048576 * 2;
        u16* whh0l = (u16*)(W + o); o += 1048576 * 2;
        u16* wih1h = (u16*)(W + o); o += 1048576 * 2;
        u16* wih1l = (u16*)(W + o); o += 1048576 * 2;
        u16* whh1h = (u16*)(W + o); o += 1048576 * 2;
        u16* whh1l = (u16*)(W + o); o += 1048576 * 2;

        zero_kernel<<<(int)((ZBYTES / 4 + 255) / 256), 256, 0, stream>>>((unsigned*)d_ws, (int)(ZBYTES / 4));
        split_kernel<<<2048, 256, 0, stream>>>(x, xhi, xlo, (int)XN);
        split_kernel<<<512, 256, 0, stream>>>(W_ih0, wih0h, wih0l, 131072);
        split_kernel<<<2048, 256, 0, stream>>>(W_hh0, whh0h, whh0l, 1048576);
        split_kernel<<<2048, 256, 0, stream>>>(W_ih1, wih1h, wih1l, 1048576);
        split_kernel<<<2048, 256, 0, stream>>>(W_hh1, whh1h, whh1l, 1048576);

        lstm_persist<<<256, 512, 0, stream>>>(
            xhi, xlo,
            wih0h, wih0l, whh0h, whh0l,
            wih1h, wih1l, whh1h, whh1l,
            b_ih0, b_hh0, b_ih1, b_hh1,
            h0hi0, h0lo0, h0hi1, h0lo1,
            h1hi0, h1lo0, h1hi1, h1lo1,
            h1last, flags);

        dim3 grid_fc1(BB / 16, 512 / 128);
        gemm_step<1><<<grid_fc1, 256, 0, stream>>>(
            h1last, HH, HH, W_fc1, nullptr, 0, nullptr,
            b_fc1, nullptr, nullptr, nullptr, zfc);
        fc2_kernel<<<BB, 64, 0, stream>>>(zfc, W_fc2, b_fc2, out);
        return;
    }

    // -------- fallback: fp32 path --------
    float* wsf = (float*)d_ws;
    float* h0a = wsf + 0 * S;
    float* c0  = wsf + 1 * S;
    float* h1a = wsf + 2 * S;
    float* c1  = wsf + 3 * S;
    float* h0b = wsf + 4 * S;
    float* h1b = wsf + 5 * S;
    float* zb  = wsf + 6 * S;
    float* h0buf[2] = {h0a, h0b};
    float* h1buf[2] = {h1a, h1b};

    zero_f_kernel<<<(int)((4 * S + 255) / 256), 256, 0, stream>>>(wsf, (int)(4 * S));

    dim3 grid_lstm(BB / 16, HH / 32);
    for (int t = 0; t < TLEN; ++t) {
        const float* xt = x + (size_t)t * DD;
        gemm_lstm_f32<<<grid_lstm, 256, 0, stream>>>(
            xt, TLEN * DD, DD, W_ih0,
            h0buf[t & 1], HH, W_hh0,
            b_ih0, b_hh0, c0, c0, h0buf[(t + 1) & 1]);
        gemm_lstm_f32<<<grid_lstm, 256, 0, stream>>>(
            h0buf[(t + 1) & 1], HH, HH, W_ih1,
            h1buf[t & 1], HH, W_hh1,
            b_ih1, b_hh1, c1, c1, h1buf[(t + 1) & 1]);
    }
    dim3 grid_fc1(BB / 16, 512 / 128);
    gemm_step<1><<<grid_fc1, 256, 0, stream>>>(
        h1buf[0], HH, HH, W_fc1, nullptr, 0, nullptr,
        b_fc1, nullptr, nullptr, nullptr, zb);
    fc2_kernel<<<BB, 64, 0, stream>>>(zb, W_fc2, b_fc2, out);
}

// Round 5
// 18088.852 us; speedup vs baseline: 4.3863x; 1.2283x over previous
//
#include <hip/hip_runtime.h>
#include <math.h>

typedef unsigned short u16;
typedef __attribute__((ext_vector_type(8))) short short8;
typedef __attribute__((ext_vector_type(4))) float float4v;

#define HH   512
#define BB   256
#define TLEN 512
#define DD   64

__device__ __forceinline__ float sigm(float x) { return 1.0f / (1.0f + __expf(-x)); }

__device__ __forceinline__ u16 bf16rn(float v) {
    unsigned u = __float_as_uint(v);
    u += 0x7fffu + ((u >> 16) & 1u);
    return (u16)(u >> 16);
}
__device__ __forceinline__ float bf16tf(u16 h) { return __uint_as_float(((unsigned)h) << 16); }

__device__ __forceinline__ float4v mfma16(short8 a, short8 b, float4v c) {
    return __builtin_amdgcn_mfma_f32_16x16x32_bf16(a, b, c, 0, 0, 0);
}

// ---------------- precompute kernels ----------------

__global__ __launch_bounds__(256) void split_kernel(const float* __restrict__ src,
                                                    u16* __restrict__ hi, u16* __restrict__ lo, int n)
{
    for (int i = blockIdx.x * 256 + threadIdx.x; i < n; i += gridDim.x * 256) {
        float v = src[i];
        u16 h = bf16rn(v);
        hi[i] = h;
        lo[i] = bf16rn(v - bf16tf(h));
    }
}

__global__ __launch_bounds__(256) void zero_kernel(unsigned* p, int n)
{
    int i = blockIdx.x * 256 + threadIdx.x;
    if (i < n) p[i] = 0u;
}

// ---------------- K-range GEMM: 64x32 tile partial over N chunks ----------------
// Wave computes acc[4 mtiles][2 ntiles] over chunks 0..N-1 (k = c*32).
// Pointers pre-offset to the wave's k-base; aoff/boff carry row*ld + kq (lane-varying).
template <int N>
__device__ __forceinline__ void gemm_range(
    const u16* __restrict__ Ah, const u16* __restrict__ Al,
    const u16* __restrict__ Bh, const u16* __restrict__ Bl,
    const size_t (&aoff)[4], const size_t (&boff)[2],
    float4v (&acc)[4][2])
{
    short8 rAh[2][4], rAl[2][4], rBh[2][2], rBl[2][2];
#pragma unroll
    for (int mt = 0; mt < 4; ++mt) {
        rAh[0][mt] = *(const short8*)(Ah + aoff[mt]);
        rAl[0][mt] = *(const short8*)(Al + aoff[mt]);
    }
#pragma unroll
    for (int nt = 0; nt < 2; ++nt) {
        rBh[0][nt] = *(const short8*)(Bh + boff[nt]);
        rBl[0][nt] = *(const short8*)(Bl + boff[nt]);
    }
    if (N > 1) {
#pragma unroll
        for (int mt = 0; mt < 4; ++mt) {
            rAh[1][mt] = *(const short8*)(Ah + aoff[mt] + 32);
            rAl[1][mt] = *(const short8*)(Al + aoff[mt] + 32);
        }
#pragma unroll
        for (int nt = 0; nt < 2; ++nt) {
            rBh[1][nt] = *(const short8*)(Bh + boff[nt] + 32);
            rBl[1][nt] = *(const short8*)(Bl + boff[nt] + 32);
        }
    }
#pragma unroll
    for (int c = 0; c < N; ++c) {
        const int s = c & 1;
#pragma unroll
        for (int mt = 0; mt < 4; ++mt)
#pragma unroll
            for (int nt = 0; nt < 2; ++nt) {
                acc[mt][nt] = mfma16(rAh[s][mt], rBh[s][nt], acc[mt][nt]);
                acc[mt][nt] = mfma16(rAh[s][mt], rBl[s][nt], acc[mt][nt]);
                acc[mt][nt] = mfma16(rAl[s][mt], rBh[s][nt], acc[mt][nt]);
            }
        if (c + 2 < N) {   // refill consumed slot with chunk c+2 (overlaps next chunk's MFMAs)
#pragma unroll
            for (int mt = 0; mt < 4; ++mt) {
                rAh[s][mt] = *(const short8*)(Ah + aoff[mt] + (size_t)(c + 2) * 32);
                rAl[s][mt] = *(const short8*)(Al + aoff[mt] + (size_t)(c + 2) * 32);
            }
#pragma unroll
            for (int nt = 0; nt < 2; ++nt) {
                rBh[s][nt] = *(const short8*)(Bh + boff[nt] + (size_t)(c + 2) * 32);
                rBl[s][nt] = *(const short8*)(Bl + boff[nt] + (size_t)(c + 2) * 32);
            }
        }
    }
}

// ---------------- grid barrier: distributed flags, relaxed polling ----------------
// flags[i*32]: step block i completed. gen = flags[8192].

__device__ __forceinline__ void gridbar(unsigned* flags, unsigned* gen,
                                        unsigned it, int tid, int bid)
{
    __syncthreads();                       // all waves' stores issued & drained (vmcnt before barrier)
    if (tid == 0) {
        __threadfence();                   // writeback: h stores visible device-wide
        __hip_atomic_store(&flags[bid * 32], it + 1, __ATOMIC_RELEASE, __HIP_MEMORY_SCOPE_AGENT);
    }
    if (bid == 0) {
        if (tid < 256) {
            while (__hip_atomic_load(&flags[tid * 32], __ATOMIC_RELAXED, __HIP_MEMORY_SCOPE_AGENT) < it + 1)
                __builtin_amdgcn_s_sleep(1);
        }
        __syncthreads();
        if (tid == 0)
            __hip_atomic_store(gen, it + 1, __ATOMIC_RELEASE, __HIP_MEMORY_SCOPE_AGENT);
    }
    if (tid == 0) {
        while (__hip_atomic_load(gen, __ATOMIC_RELAXED, __HIP_MEMORY_SCOPE_AGENT) < it + 1)
            __builtin_amdgcn_s_sleep(1);
        __threadfence();                   // invalidate stale cached h before reading
    }
    __syncthreads();
}

// ---------------- persistent kernel: merged roles, K-split waves ----------------
// 256 blocks x 512 threads, 1 block/CU. Block = (mquart, jslice):
//   bid = mquart*64 + jslice  -> bid%8 == jslice%8 (XCD weight locality)
//   m0 = mquart*64 (64 batch rows), j = jslice*8..+8 (8 h-units, n=32 gate cols)
// Each iteration: L0 step t=it (skip it==512) and L1 step t=it-1 (skip it==0).
// 8 waves split the 50 K-chunks: wv0-2 -> L0 (x·Wih0 + h0·Whh0, 18), wv3-7 -> L1 (h0·Wih1 + h1·Whh1, 32).
// Partials combined in LDS; c-state in registers; weights streamed from L2 every step.

__global__ __launch_bounds__(512, 2) void lstm_persist(
    const u16* __restrict__ xhi, const u16* __restrict__ xlo,
    const u16* __restrict__ wih0h, const u16* __restrict__ wih0l,
    const u16* __restrict__ whh0h, const u16* __restrict__ whh0l,
    const u16* __restrict__ wih1h, const u16* __restrict__ wih1l,
    const u16* __restrict__ whh1h, const u16* __restrict__ whh1l,
    const float* __restrict__ bi0, const float* __restrict__ bh0,
    const float* __restrict__ bi1, const float* __restrict__ bh1,
    u16* h0hi0, u16* h0lo0, u16* h0hi1, u16* h0lo1,
    u16* h1hi0, u16* h1lo0, u16* h1hi1, u16* h1lo1,
    float* h1last, unsigned* flags)
{
    __shared__ float sEp[8][4][16][33];    // [wave][mtile][row][n col] partials

    const int tid  = threadIdx.x;
    const int lane = tid & 63;
    const int wv   = tid >> 6;             // 0..7
    const int bid  = blockIdx.x;
    const int jslice = bid & 63;
    const int mquart = bid >> 6;
    const int m0  = mquart * 64;
    const int nsel = lane & 15;
    const int kq   = (lane >> 4) * 8;
    unsigned* gen = flags + 8192;

    // ---- per-lane row offsets ----
    size_t aoffH[4], aoffX[4], boffH[2], boffX[2];
#pragma unroll
    for (int mt = 0; mt < 4; ++mt) {
        const int arow = m0 + mt * 16 + nsel;
        aoffH[mt] = (size_t)arow * HH + kq;
        aoffX[mt] = (size_t)arow * (TLEN * DD) + kq;
    }
#pragma unroll
    for (int nt = 0; nt < 2; ++nt) {
        const int n = nt * 16 + nsel;          // 0..31: gate g = n>>3, unit jl = n&7
        const int brow = (n >> 3) * HH + jslice * 8 + (n & 7);
        boffH[nt] = (size_t)brow * HH + kq;
        boffX[nt] = (size_t)brow * DD + kq;
    }

    // ---- epilogue constants: thread -> (m = tid>>3, jl = tid&7) ----
    const int em  = tid >> 3;
    const int ejl = tid & 7;
    const int emt = em >> 4, erow = em & 15;
    const int jglob = jslice * 8 + ejl;
    float bias0[4], bias1[4];
#pragma unroll
    for (int q = 0; q < 4; ++q) {
        bias0[q] = bi0[q * HH + jglob] + bh0[q * HH + jglob];
        bias1[q] = bi1[q * HH + jglob] + bh1[q * HH + jglob];
    }
    const size_t eoff = (size_t)(m0 + em) * HH + jglob;

    float creg0 = 0.f, creg1 = 0.f;        // persistent cell states

    for (int it = 0; it <= TLEN; ++it) {
        const int rb = it & 1;
        const u16* h0r_h = rb ? h0hi1 : h0hi0;
        const u16* h0r_l = rb ? h0lo1 : h0lo0;
        const u16* h1r_h = rb ? h1hi1 : h1hi0;
        const u16* h1r_l = rb ? h1lo1 : h1lo0;
        u16* h0w_h = rb ? h0hi0 : h0hi1;
        u16* h0w_l = rb ? h0lo0 : h0lo1;
        u16* h1w_h = rb ? h1hi0 : h1hi1;
        u16* h1w_l = rb ? h1lo0 : h1lo1;
        const int itx = (it < TLEN) ? it : (TLEN - 1);
        const u16* xh_t = xhi + (size_t)itx * DD;
        const u16* xl_t = xlo + (size_t)itx * DD;

        float4v acc[4][2];
#pragma unroll
        for (int mt = 0; mt < 4; ++mt)
#pragma unroll
            for (int nt = 0; nt < 2; ++nt) { acc[mt][nt][0]=0.f; acc[mt][nt][1]=0.f; acc[mt][nt][2]=0.f; acc[mt][nt][3]=0.f; }

        // ---- K-split wave dispatch (chunk = 32 k) ----
        if (wv == 0) {          // x(2 chunks, K=64) + h0.Whh0 chunks [0,4)
            gemm_range<2>(xh_t, xl_t, wih0h, wih0l, aoffX, boffX, acc);
            gemm_range<4>(h0r_h, h0r_l, whh0h, whh0l, aoffH, boffH, acc);
        } else if (wv == 1) {   // h0.Whh0 [4,10)
            gemm_range<6>(h0r_h + 4*32, h0r_l + 4*32, whh0h + 4*32, whh0l + 4*32, aoffH, boffH, acc);
        } else if (wv == 2) {   // h0.Whh0 [10,16)
            gemm_range<6>(h0r_h + 10*32, h0r_l + 10*32, whh0h + 10*32, whh0l + 10*32, aoffH, boffH, acc);
        } else if (wv == 3) {   // h0.Wih1 [0,7)
            gemm_range<7>(h0r_h, h0r_l, wih1h, wih1l, aoffH, boffH, acc);
        } else if (wv == 4) {   // h0.Wih1 [7,14)
            gemm_range<7>(h0r_h + 7*32, h0r_l + 7*32, wih1h + 7*32, wih1l + 7*32, aoffH, boffH, acc);
        } else if (wv == 5) {   // h0.Wih1 [14,16) + h1.Whh1 [0,4)
            gemm_range<2>(h0r_h + 14*32, h0r_l + 14*32, wih1h + 14*32, wih1l + 14*32, aoffH, boffH, acc);
            gemm_range<4>(h1r_h, h1r_l, whh1h, whh1l, aoffH, boffH, acc);
        } else if (wv == 6) {   // h1.Whh1 [4,10)
            gemm_range<6>(h1r_h + 4*32, h1r_l + 4*32, whh1h + 4*32, whh1l + 4*32, aoffH, boffH, acc);
        } else {                // h1.Whh1 [10,16)
            gemm_range<6>(h1r_h + 10*32, h1r_l + 10*32, whh1h + 10*32, whh1l + 10*32, aoffH, boffH, acc);
        }

        // ---- stage partials ----
#pragma unroll
        for (int mt = 0; mt < 4; ++mt)
#pragma unroll
            for (int nt = 0; nt < 2; ++nt)
#pragma unroll
                for (int r = 0; r < 4; ++r)
                    sEp[wv][mt][(lane >> 4) * 4 + r][nt * 16 + nsel] = acc[mt][nt][r];
        __syncthreads();

        // ---- epilogues (c in registers) ----
        if (it < TLEN) {       // L0, gates = sum of wave 0..2 partials
            float g[4];
#pragma unroll
            for (int q = 0; q < 4; ++q) {
                const int col = q * 8 + ejl;
                g[q] = sEp[0][emt][erow][col] + sEp[1][emt][erow][col]
                     + sEp[2][emt][erow][col] + bias0[q];
            }
            float cn = sigm(g[1]) * creg0 + sigm(g[0]) * tanhf(g[2]);
            float h  = sigm(g[3]) * tanhf(cn);
            creg0 = cn;
            u16 hv = bf16rn(h);
            h0w_h[eoff] = hv;
            h0w_l[eoff] = bf16rn(h - bf16tf(hv));
        }
        if (it > 0) {          // L1 (step it-1), gates = sum of wave 3..7 partials
            float g[4];
#pragma unroll
            for (int q = 0; q < 4; ++q) {
                const int col = q * 8 + ejl;
                g[q] = sEp[3][emt][erow][col] + sEp[4][emt][erow][col]
                     + sEp[5][emt][erow][col] + sEp[6][emt][erow][col]
                     + sEp[7][emt][erow][col] + bias1[q];
            }
            float cn = sigm(g[1]) * creg1 + sigm(g[0]) * tanhf(g[2]);
            float h  = sigm(g[3]) * tanhf(cn);
            creg1 = cn;
            u16 hv = bf16rn(h);
            h1w_h[eoff] = hv;
            h1w_l[eoff] = bf16rn(h - bf16tf(hv));
            if (it == TLEN) h1last[eoff] = h;
        }

        if (it < TLEN) gridbar(flags, gen, (unsigned)it, tid, bid);
    }
}

// ---------------- FC head (proven) ----------------

template <int MODE>
__global__ __launch_bounds__(256) void gemm_step(
    const float* __restrict__ A1, int lda1, int K1, const float* __restrict__ W1,
    const float* __restrict__ b1, float* __restrict__ h_out)
{
    __shared__ float sA[16][33];
    __shared__ float sW[128][33];

    const int tid = threadIdx.x;
    const int tj  = tid & 31;
    const int tg  = tid >> 5;
    const int m0  = blockIdx.x * 16;
    const int j0  = blockIdx.y * 128;

    float acc[2][4] = {{0.f, 0.f, 0.f, 0.f}, {0.f, 0.f, 0.f, 0.f}};

    for (int kb = 0; kb < K1; kb += 32) {
        __syncthreads();
        {
            int idxq = tid;
#pragma unroll
            for (int r = 0; r < 2; ++r, idxq += 256) {
                int row = idxq >> 5, col = idxq & 31;
                sA[row][col] = A1[(m0 + row) * lda1 + kb + col];
            }
        }
        {
#pragma unroll
            for (int i = 0; i < 16; ++i) {
                int idxq = i * 256 + tid;
                int row = idxq >> 5, col = idxq & 31;
                sW[row][col] = W1[(j0 + row) * K1 + kb + col];
            }
        }
        __syncthreads();
#pragma unroll
        for (int k = 0; k < 32; ++k) {
            float a0 = sA[tg][k];
            float a1 = sA[tg + 8][k];
            float w0 = sW[tj][k];
            float w1 = sW[32 + tj][k];
            float w2 = sW[64 + tj][k];
            float w3 = sW[96 + tj][k];
            acc[0][0] += a0 * w0; acc[0][1] += a0 * w1;
            acc[0][2] += a0 * w2; acc[0][3] += a0 * w3;
            acc[1][0] += a1 * w0; acc[1][1] += a1 * w1;
            acc[1][2] += a1 * w2; acc[1][3] += a1 * w3;
        }
    }

#pragma unroll
    for (int r = 0; r < 2; ++r) {
        int m = m0 + tg + r * 8;
#pragma unroll
        for (int q = 0; q < 4; ++q) {
            int nn = j0 + q * 32 + tj;
            float v = acc[r][q] + b1[nn];
            h_out[m * HH + nn] = fmaxf(v, 0.f);
        }
    }
}

__global__ __launch_bounds__(64) void fc2_kernel(
    const float* __restrict__ z, const float* __restrict__ W,
    const float* __restrict__ b, float* __restrict__ out)
{
    int m = blockIdx.x;
    int lane = threadIdx.x;
    float zr[8];
#pragma unroll
    for (int u = 0; u < 8; ++u) zr[u] = z[m * 512 + u * 64 + lane];
#pragma unroll
    for (int o = 0; o < 8; ++o) {
        float s = 0.f;
#pragma unroll
        for (int u = 0; u < 8; ++u) s += zr[u] * W[o * 512 + u * 64 + lane];
#pragma unroll
        for (int off = 32; off > 0; off >>= 1) s += __shfl_down(s, off);
        if (lane == 0) out[m * 8 + o] = s + b[o];
    }
}

__global__ __launch_bounds__(256) void zero_f_kernel(float* p, int n)
{
    int i = blockIdx.x * 256 + threadIdx.x;
    if (i < n) p[i] = 0.f;
}

// fp32 LSTM step for fallback path
__global__ __launch_bounds__(256) void gemm_lstm_f32(
    const float* __restrict__ A1, int lda1, int K1, const float* __restrict__ W1,
    const float* __restrict__ A2, int K2, const float* __restrict__ W2,
    const float* __restrict__ b1, const float* __restrict__ b2,
    const float* __restrict__ c_in, float* __restrict__ c_out,
    float* __restrict__ h_out)
{
    __shared__ float sA[16][33];
    __shared__ float sW[128][33];

    const int tid = threadIdx.x;
    const int tj  = tid & 31;
    const int tg  = tid >> 5;
    const int m0  = blockIdx.x * 16;
    const int j0  = blockIdx.y * 32;

    float acc[2][4] = {{0.f, 0.f, 0.f, 0.f}, {0.f, 0.f, 0.f, 0.f}};

    for (int seg = 0; seg < 2; ++seg) {
        const float* A  = seg ? A2 : A1;
        const float* W  = seg ? W2 : W1;
        const int    K  = seg ? K2 : K1;
        const int    ld = seg ? HH : lda1;
        for (int kb = 0; kb < K; kb += 32) {
            __syncthreads();
            {
                int idxq = tid;
#pragma unroll
                for (int r = 0; r < 2; ++r, idxq += 256) {
                    int row = idxq >> 5, col = idxq & 31;
                    sA[row][col] = A[(m0 + row) * ld + kb + col];
                }
            }
            {
#pragma unroll
                for (int i = 0; i < 16; ++i) {
                    int idxq = i * 256 + tid;
                    int row = idxq >> 5, col = idxq & 31;
                    int grw = (row >> 5) * HH + j0 + (row & 31);
                    sW[row][col] = W[grw * K + kb + col];
                }
            }
            __syncthreads();
#pragma unroll
            for (int k = 0; k < 32; ++k) {
                float a0 = sA[tg][k];
                float a1 = sA[tg + 8][k];
                float w0 = sW[tj][k];
                float w1 = sW[32 + tj][k];
                float w2 = sW[64 + tj][k];
                float w3 = sW[96 + tj][k];
                acc[0][0] += a0 * w0; acc[0][1] += a0 * w1;
                acc[0][2] += a0 * w2; acc[0][3] += a0 * w3;
                acc[1][0] += a1 * w0; acc[1][1] += a1 * w1;
                acc[1][2] += a1 * w2; acc[1][3] += a1 * w3;
            }
        }
    }

    const int j = j0 + tj;
    const float bi = b1[j] + b2[j];
    const float bf = b1[HH + j] + b2[HH + j];
    const float bg = b1[2 * HH + j] + b2[2 * HH + j];
    const float bo = b1[3 * HH + j] + b2[3 * HH + j];
#pragma unroll
    for (int r = 0; r < 2; ++r) {
        int m = m0 + tg + r * 8;
        float gi = acc[r][0] + bi;
        float gf = acc[r][1] + bf;
        float gg = acc[r][2] + bg;
        float go = acc[r][3] + bo;
        float cp = c_in[m * HH + j];
        float c  = sigm(gf) * cp + sigm(gi) * tanhf(gg);
        float h  = sigm(go) * tanhf(c);
        c_out[m * HH + j] = c;
        h_out[m * HH + j] = h;
    }
}

// ---------------- host ----------------

extern "C" void kernel_launch(void* const* d_in, const int* in_sizes, int n_in,
                              void* d_out, int out_size, void* d_ws, size_t ws_size,
                              hipStream_t stream)
{
    const float* x     = (const float*)d_in[0];
    const float* W_ih0 = (const float*)d_in[1];
    const float* W_hh0 = (const float*)d_in[2];
    const float* b_ih0 = (const float*)d_in[3];
    const float* b_hh0 = (const float*)d_in[4];
    const float* W_ih1 = (const float*)d_in[5];
    const float* W_hh1 = (const float*)d_in[6];
    const float* b_ih1 = (const float*)d_in[7];
    const float* b_hh1 = (const float*)d_in[8];
    const float* W_fc1 = (const float*)d_in[9];
    const float* b_fc1 = (const float*)d_in[10];
    const float* W_fc2 = (const float*)d_in[11];
    const float* b_fc2 = (const float*)d_in[12];
    float* out = (float*)d_out;

    const size_t S  = (size_t)BB * HH;        // 131072 elems
    const size_t SB = S * sizeof(u16);        // 262144 B
    const size_t SF = S * sizeof(float);      // 524288 B
    const size_t XN = (size_t)BB * TLEN * DD; // 8388608 elems
    const size_t FLAGB = (8192 + 32) * 4;     // flags[256*32] + gen line

    const size_t NEED = FLAGB + 8 * SB + 2 * SF + 2 * XN * 2 +
                        2 * 131072 * 2 + 6 * 1048576 * 2;

    if (ws_size >= NEED) {
        char* W = (char*)d_ws;
        size_t o = 0;
        // ---- zero region: flags + initial-state buffers ----
        unsigned* flags = (unsigned*)(W + o); o += FLAGB;
        u16* h0hi0 = (u16*)(W + o); o += SB;
        u16* h0lo0 = (u16*)(W + o); o += SB;
        u16* h1hi1 = (u16*)(W + o); o += SB;
        u16* h1lo1 = (u16*)(W + o); o += SB;
        const size_t ZBYTES = o;
        // ---- rest ----
        u16* h0hi1 = (u16*)(W + o); o += SB;
        u16* h0lo1 = (u16*)(W + o); o += SB;
        u16* h1hi0 = (u16*)(W + o); o += SB;
        u16* h1lo0 = (u16*)(W + o); o += SB;
        float* h1last = (float*)(W + o); o += SF;
        float* zfc    = (float*)(W + o); o += SF;
        u16* xhi = (u16*)(W + o); o += XN * 2;
        u16* xlo = (u16*)(W + o); o += XN * 2;
        u16* wih0h = (u16*)(W + o); o += 131072 * 2;
        u16* wih0l = (u16*)(W + o); o += 131072 * 2;
        u16* whh0h = (u16*)(W + o); o += 1048576 * 2;
        u16* whh0l = (u16*)(W + o); o += 1048576 * 2;
        u16* wih1h = (u16*)(W + o); o += 1048576 * 2;
        u16* wih1l = (u16*)(W + o); o += 1048576 * 2;
        u16* whh1h = (u16*)(W + o); o += 1048576 * 2;
        u16* whh1l = (u16*)(W + o); o += 1048576 * 2;

        zero_kernel<<<(int)((ZBYTES / 4 + 255) / 256), 256, 0, stream>>>((unsigned*)d_ws, (int)(ZBYTES / 4));
        split_kernel<<<2048, 256, 0, stream>>>(x, xhi, xlo, (int)XN);
        split_kernel<<<512, 256, 0, stream>>>(W_ih0, wih0h, wih0l, 131072);
        split_kernel<<<2048, 256, 0, stream>>>(W_hh0, whh0h, whh0l, 1048576);
        split_kernel<<<2048, 256, 0, stream>>>(W_ih1, wih1h, wih1l, 1048576);
        split_kernel<<<2048, 256, 0, stream>>>(W_hh1, whh1h, whh1l, 1048576);

        lstm_persist<<<256, 512, 0, stream>>>(
            xhi, xlo,
            wih0h, wih0l, whh0h, whh0l,
            wih1h, wih1l, whh1h, whh1l,
            b_ih0, b_hh0, b_ih1, b_hh1,
            h0hi0, h0lo0, h0hi1, h0lo1,
            h1hi0, h1lo0, h1hi1, h1lo1,
            h1last, flags);

        dim3 grid_fc1(BB / 16, 512 / 128);
        gemm_step<1><<<grid_fc1, 256, 0, stream>>>(h1last, HH, HH, W_fc1, b_fc1, zfc);
        fc2_kernel<<<BB, 64, 0, stream>>>(zfc, W_fc2, b_fc2, out);
        return;
    }

    // -------- fallback: fp32 path --------
    float* wsf = (float*)d_ws;
    float* h0a = wsf + 0 * S;
    float* c0  = wsf + 1 * S;
    float* h1a = wsf + 2 * S;
    float* c1  = wsf + 3 * S;
    float* h0b = wsf + 4 * S;
    float* h1b = wsf + 5 * S;
    float* zb  = wsf + 6 * S;
    float* h0buf[2] = {h0a, h0b};
    float* h1buf[2] = {h1a, h1b};

    zero_f_kernel<<<(int)((4 * S + 255) / 256), 256, 0, stream>>>(wsf, (int)(4 * S));

    dim3 grid_lstm(BB / 16, HH / 32);
    for (int t = 0; t < TLEN; ++t) {
        const float* xt = x + (size_t)t * DD;
        gemm_lstm_f32<<<grid_lstm, 256, 0, stream>>>(
            xt, TLEN * DD, DD, W_ih0,
            h0buf[t & 1], HH, W_hh0,
            b_ih0, b_hh0, c0, c0, h0buf[(t + 1) & 1]);
        gemm_lstm_f32<<<grid_lstm, 256, 0, stream>>>(
            h0buf[(t + 1) & 1], HH, HH, W_ih1,
            h1buf[t & 1], HH, W_hh1,
            b_ih1, b_hh1, c1, c1, h1buf[(t + 1) & 1]);
    }
    dim3 grid_fc1(BB / 16, 512 / 128);
    gemm_step<1><<<grid_fc1, 256, 0, stream>>>(h1buf[0], HH, HH, W_fc1, b_fc1, zb);
    fc2_kernel<<<BB, 64, 0, stream>>>(zb, W_fc2, b_fc2, out);
}

// Round 6
// 16524.409 us; speedup vs baseline: 4.8016x; 1.0947x over previous
//
#include <hip/hip_runtime.h>
#include <math.h>

typedef unsigned short u16;
typedef __attribute__((ext_vector_type(8))) short short8;
typedef __attribute__((ext_vector_type(4))) float float4v;

#define HH   512
#define BB   256
#define TLEN 512
#define DD   64

__device__ __forceinline__ float sigm(float x) { return 1.0f / (1.0f + __expf(-x)); }

__device__ __forceinline__ u16 bf16rn(float v) {
    unsigned u = __float_as_uint(v);
    u += 0x7fffu + ((u >> 16) & 1u);
    return (u16)(u >> 16);
}
__device__ __forceinline__ float bf16tf(u16 h) { return __uint_as_float(((unsigned)h) << 16); }

__device__ __forceinline__ float4v mfma16(short8 a, short8 b, float4v c) {
    return __builtin_amdgcn_mfma_f32_16x16x32_bf16(a, b, c, 0, 0, 0);
}

// ---------------- precompute kernels ----------------

__global__ __launch_bounds__(256) void split_kernel(const float* __restrict__ src,
                                                    u16* __restrict__ hi, u16* __restrict__ lo, int n)
{
    for (int i = blockIdx.x * 256 + threadIdx.x; i < n; i += gridDim.x * 256) {
        float v = src[i];
        u16 h = bf16rn(v);
        hi[i] = h;
        lo[i] = bf16rn(v - bf16tf(h));
    }
}

// x[B][T*D] -> xT[t][m][d] hi/lo split
__global__ __launch_bounds__(256) void txpose_kernel(const float* __restrict__ x,
                                                     u16* __restrict__ hi, u16* __restrict__ lo)
{
    const int N = BB * TLEN * DD;
    for (int i = blockIdx.x * 256 + threadIdx.x; i < N; i += gridDim.x * 256) {
        int d = i & 63, m = (i >> 6) & 255, t = i >> 14;
        float v = x[(size_t)m * (TLEN * DD) + t * DD + d];
        u16 h = bf16rn(v);
        hi[i] = h;
        lo[i] = bf16rn(v - bf16tf(h));
    }
}

__global__ __launch_bounds__(256) void zero_kernel(unsigned* p, int n)
{
    int i = blockIdx.x * 256 + threadIdx.x;
    if (i < n) p[i] = 0u;
}

// ---------------- K-loop: A from global (depth-4 ring), B from LDS (depth-2) ----------------
// Wave tile: 32 m (2 mtiles) x 32 n (2 ntiles), NC chunks of k=32.
// First NX chunks read A from xT (stride DD), rest from h (stride HH).
template <int NC, int NX>
__device__ __forceinline__ void kloop(
    const u16* __restrict__ axh, const u16* __restrict__ axl, const size_t (&xoff)[2],
    const u16* __restrict__ ahh, const u16* __restrict__ ahl, const size_t (&hoff)[2],
    const short* __restrict__ sB, int bbase, float4v (&acc)[2][2])
{
    auto aph = [&](int c, int mt) -> const short8* {
        return (c < NX) ? (const short8*)(axh + xoff[mt] + (size_t)c * 32)
                        : (const short8*)(ahh + hoff[mt] + (size_t)(c - NX) * 32);
    };
    auto apl = [&](int c, int mt) -> const short8* {
        return (c < NX) ? (const short8*)(axl + xoff[mt] + (size_t)c * 32)
                        : (const short8*)(ahl + hoff[mt] + (size_t)(c - NX) * 32);
    };
    short8 Ah[4][2], Al[4][2], Bh[2][2], Bl[2][2];
#pragma unroll
    for (int p = 0; p < 4 && p < NC; ++p)
#pragma unroll
        for (int mt = 0; mt < 2; ++mt) { Ah[p][mt] = *aph(p, mt); Al[p][mt] = *apl(p, mt); }
#pragma unroll
    for (int p = 0; p < 2 && p < NC; ++p)
#pragma unroll
        for (int nt = 0; nt < 2; ++nt) {
            Bh[p][nt] = *(const short8*)(sB + bbase + ((p * 2 + nt) * 2 + 0) * 512);
            Bl[p][nt] = *(const short8*)(sB + bbase + ((p * 2 + nt) * 2 + 1) * 512);
        }
#pragma unroll
    for (int c = 0; c < NC; ++c) {
        const int sa = c & 3, sb = c & 1;
#pragma unroll
        for (int mt = 0; mt < 2; ++mt)
#pragma unroll
            for (int nt = 0; nt < 2; ++nt) {
                acc[mt][nt] = mfma16(Ah[sa][mt], Bh[sb][nt], acc[mt][nt]);
                acc[mt][nt] = mfma16(Ah[sa][mt], Bl[sb][nt], acc[mt][nt]);
                acc[mt][nt] = mfma16(Al[sa][mt], Bh[sb][nt], acc[mt][nt]);
            }
        if (c + 4 < NC) {
#pragma unroll
            for (int mt = 0; mt < 2; ++mt) { Ah[sa][mt] = *aph(c + 4, mt); Al[sa][mt] = *apl(c + 4, mt); }
        }
        if (c + 2 < NC) {
#pragma unroll
            for (int nt = 0; nt < 2; ++nt) {
                Bh[sb][nt] = *(const short8*)(sB + bbase + (((c + 2) * 2 + nt) * 2 + 0) * 512);
                Bl[sb][nt] = *(const short8*)(sB + bbase + (((c + 2) * 2 + nt) * 2 + 1) * 512);
            }
        }
    }
}

// ---------------- grid barrier (r5-proven): distributed flags, relaxed polling ----------------

__device__ __forceinline__ void gridbar(unsigned* flags, unsigned* gen,
                                        unsigned it, int tid, int bid)
{
    __syncthreads();
    if (tid == 0) {
        __threadfence();
        __hip_atomic_store(&flags[bid * 32], it + 1, __ATOMIC_RELEASE, __HIP_MEMORY_SCOPE_AGENT);
    }
    if (bid == 0) {
        if (tid < 256) {
            while (__hip_atomic_load(&flags[tid * 32], __ATOMIC_RELAXED, __HIP_MEMORY_SCOPE_AGENT) < it + 1)
                __builtin_amdgcn_s_sleep(1);
        }
        __syncthreads();
        if (tid == 0)
            __hip_atomic_store(gen, it + 1, __ATOMIC_RELEASE, __HIP_MEMORY_SCOPE_AGENT);
    }
    if (tid == 0) {
        while (__hip_atomic_load(gen, __ATOMIC_RELAXED, __HIP_MEMORY_SCOPE_AGENT) < it + 1)
            __builtin_amdgcn_s_sleep(1);
        __threadfence();
    }
    __syncthreads();
}

// ---------------- persistent kernel: LDS-resident weights ----------------
// 256 blocks x 512 threads, 1 block/CU (147456 B LDS).
// bid<128 -> L0; else L1. q=bid&127: jslice=q>>1 (8 units), mhalf=q&1 (128 rows).
// bid%8 fixes XCD; mhalf=q&1 => all blocks on an XCD share the same m-half (L2 locality).
// 8 waves = 4 msegs (32 rows) x 2 khalfs. Weights in LDS in MFMA-frag order.

__global__ __launch_bounds__(512, 2) void lstm_persist(
    const u16* __restrict__ xTh, const u16* __restrict__ xTl,
    const u16* __restrict__ wih0h, const u16* __restrict__ wih0l,
    const u16* __restrict__ whh0h, const u16* __restrict__ whh0l,
    const u16* __restrict__ wih1h, const u16* __restrict__ wih1l,
    const u16* __restrict__ whh1h, const u16* __restrict__ whh1l,
    const float* __restrict__ bi0, const float* __restrict__ bh0,
    const float* __restrict__ bi1, const float* __restrict__ bh1,
    u16* h0hi0, u16* h0lo0, u16* h0hi1, u16* h0lo1,
    u16* h1hi0, u16* h1lo0, u16* h1hi1, u16* h1lo1,
    float* h1last, unsigned* flags)
{
    __shared__ short smem[73728];          // 128 KB weights + 16 KB staging
    float* sEp = (float*)(smem + 65536);

    const int tid  = threadIdx.x;
    const int lane = tid & 63;
    const int wv   = tid >> 6;
    const int mseg = wv & 3, khalf = wv >> 2;
    const int bid  = blockIdx.x;
    const bool role1 = (bid >= 128);
    const int q = bid & 127;
    const int jslice = q >> 1, mhalf = q & 1;
    const int m0 = mhalf * 128, j0 = jslice * 8;
    const int nsel = lane & 15, kq = (lane >> 4) * 8;
    unsigned* gen = flags + 8192;

    // ---- weight preload to LDS (once), MFMA-frag order, lane-linear ----
    if (!role1) {
        for (int g = wv; g < 72; g += 8) {
            int c = g >> 2, nt = (g >> 1) & 1, hl = g & 1;
            int n = nt * 16 + nsel;
            int grow = (n >> 3) * HH + j0 + (n & 7);
            const u16* src; size_t off;
            if (c < 2) { src = hl ? wih0l : wih0h; off = (size_t)grow * DD + c * 32 + kq; }
            else       { src = hl ? whh0l : whh0h; off = (size_t)grow * HH + (size_t)(c - 2) * 32 + kq; }
            *(short8*)&smem[g * 512 + lane * 8] = *(const short8*)(src + off);
        }
    } else {
        for (int g = wv; g < 128; g += 8) {
            int khw = g >> 6, c = (g >> 2) & 15, nt = (g >> 1) & 1, hl = g & 1;
            int n = nt * 16 + nsel;
            int grow = (n >> 3) * HH + j0 + (n & 7);
            const u16* src = khw ? (hl ? whh1l : whh1h) : (hl ? wih1l : wih1h);
            *(short8*)&smem[g * 512 + lane * 8] = *(const short8*)(src + (size_t)grow * HH + (size_t)c * 32 + kq);
        }
    }
    __syncthreads();

    // ---- constants ----
    const int ejl = lane & 7;
    const int jglob = j0 + ejl;
    const float* pbi = role1 ? bi1 : bi0;
    const float* pbh = role1 ? bh1 : bh0;
    float bias4[4];
#pragma unroll
    for (int b = 0; b < 4; ++b) bias4[b] = pbi[b * HH + jglob] + pbh[b * HH + jglob];

    size_t hoff[2], xoffb[2];
#pragma unroll
    for (int mt = 0; mt < 2; ++mt) {
        const int arow = m0 + mseg * 32 + mt * 16 + nsel;
        hoff[mt]  = (size_t)arow * HH + kq + ((!role1 && khalf) ? 7 * 32 : 0);
        xoffb[mt] = (size_t)arow * DD + kq;
    }
    const int bbase = (role1 ? khalf * 16 : (khalf ? 9 : 0)) * 2048 + lane * 8;

    float creg[2][4] = {{0.f,0.f,0.f,0.f},{0.f,0.f,0.f,0.f}};

    for (int it = 0; it <= TLEN; ++it) {
        const int rb = it & 1;
        const u16* h0r_h = rb ? h0hi1 : h0hi0;
        const u16* h0r_l = rb ? h0lo1 : h0lo0;
        const u16* h1r_h = rb ? h1hi1 : h1hi0;
        const u16* h1r_l = rb ? h1lo1 : h1lo0;
        u16* h0w_h = rb ? h0hi0 : h0hi1;
        u16* h0w_l = rb ? h0lo0 : h0lo1;
        u16* h1w_h = rb ? h1hi0 : h1hi1;
        u16* h1w_l = rb ? h1lo0 : h1lo1;
        const bool active = role1 ? (it > 0) : (it < TLEN);

        if (active) {
            float4v acc[2][2];
#pragma unroll
            for (int mt = 0; mt < 2; ++mt)
#pragma unroll
                for (int nt = 0; nt < 2; ++nt) { acc[mt][nt][0]=0.f; acc[mt][nt][1]=0.f; acc[mt][nt][2]=0.f; acc[mt][nt][3]=0.f; }

            if (role1) {
                const u16* ah = khalf ? h1r_h : h0r_h;
                const u16* al = khalf ? h1r_l : h0r_l;
                kloop<16, 0>(nullptr, nullptr, hoff, ah, al, hoff, smem, bbase, acc);
            } else if (khalf == 0) {
                size_t xoff[2] = { xoffb[0] + (size_t)it * (BB * DD), xoffb[1] + (size_t)it * (BB * DD) };
                kloop<9, 2>(xTh, xTl, xoff, h0r_h, h0r_l, hoff, smem, bbase, acc);
            } else {
                kloop<9, 0>(nullptr, nullptr, hoff, h0r_h, h0r_l, hoff, smem, bbase, acc);
            }

            if (khalf == 1) {    // stage partials (lane-linear, conflict-free)
#pragma unroll
                for (int mt = 0; mt < 2; ++mt)
#pragma unroll
                    for (int nt = 0; nt < 2; ++nt)
#pragma unroll
                        for (int r = 0; r < 4; ++r)
                            sEp[((((mseg * 2 + mt) * 2 + nt) * 4) + r) * 64 + lane] = acc[mt][nt][r];
            }
            __syncthreads();
            if (khalf == 0) {
                u16* wh = role1 ? h1w_h : h0w_h;
                u16* wl = role1 ? h1w_l : h0w_l;
#pragma unroll
                for (int mt = 0; mt < 2; ++mt)
#pragma unroll
                    for (int r = 0; r < 4; ++r) {
                        float v0 = acc[mt][0][r] + sEp[((((mseg * 2 + mt) * 2 + 0) * 4) + r) * 64 + lane];
                        float v1 = acc[mt][1][r] + sEp[((((mseg * 2 + mt) * 2 + 1) * 4) + r) * 64 + lane];
                        float p0 = __shfl_xor(v0, 8, 64);
                        float p1 = __shfl_xor(v1, 8, 64);
                        if (nsel < 8) {
                            float gi = v0 + bias4[0];
                            float gf = p0 + bias4[1];
                            float gG = v1 + bias4[2];
                            float go = p1 + bias4[3];
                            float cn = sigm(gf) * creg[mt][r] + sigm(gi) * tanhf(gG);
                            float h  = sigm(go) * tanhf(cn);
                            creg[mt][r] = cn;
                            const int m = m0 + mseg * 32 + mt * 16 + (lane >> 4) * 4 + r;
                            const size_t off = (size_t)m * HH + jglob;
                            u16 hv = bf16rn(h);
                            wh[off] = hv;
                            wl[off] = bf16rn(h - bf16tf(hv));
                            if (role1 && it == TLEN) h1last[off] = h;
                        }
                    }
            }
        }
        if (it < TLEN) gridbar(flags, gen, (unsigned)it, tid, bid);
    }
}

// ---------------- FC head (proven) ----------------

template <int MODE>
__global__ __launch_bounds__(256) void gemm_step(
    const float* __restrict__ A1, int lda1, int K1, const float* __restrict__ W1,
    const float* __restrict__ b1, float* __restrict__ h_out)
{
    __shared__ float sA[16][33];
    __shared__ float sW[128][33];

    const int tid = threadIdx.x;
    const int tj  = tid & 31;
    const int tg  = tid >> 5;
    const int m0  = blockIdx.x * 16;
    const int j0  = blockIdx.y * 128;

    float acc[2][4] = {{0.f, 0.f, 0.f, 0.f}, {0.f, 0.f, 0.f, 0.f}};

    for (int kb = 0; kb < K1; kb += 32) {
        __syncthreads();
        {
            int idxq = tid;
#pragma unroll
            for (int r = 0; r < 2; ++r, idxq += 256) {
                int row = idxq >> 5, col = idxq & 31;
                sA[row][col] = A1[(m0 + row) * lda1 + kb + col];
            }
        }
        {
#pragma unroll
            for (int i = 0; i < 16; ++i) {
                int idxq = i * 256 + tid;
                int row = idxq >> 5, col = idxq & 31;
                sW[row][col] = W1[(j0 + row) * K1 + kb + col];
            }
        }
        __syncthreads();
#pragma unroll
        for (int k = 0; k < 32; ++k) {
            float a0 = sA[tg][k];
            float a1 = sA[tg + 8][k];
            float w0 = sW[tj][k];
            float w1 = sW[32 + tj][k];
            float w2 = sW[64 + tj][k];
            float w3 = sW[96 + tj][k];
            acc[0][0] += a0 * w0; acc[0][1] += a0 * w1;
            acc[0][2] += a0 * w2; acc[0][3] += a0 * w3;
            acc[1][0] += a1 * w0; acc[1][1] += a1 * w1;
            acc[1][2] += a1 * w2; acc[1][3] += a1 * w3;
        }
    }

#pragma unroll
    for (int r = 0; r < 2; ++r) {
        int m = m0 + tg + r * 8;
#pragma unroll
        for (int p = 0; p < 4; ++p) {
            int nn = j0 + p * 32 + tj;
            float v = acc[r][p] + b1[nn];
            h_out[m * HH + nn] = fmaxf(v, 0.f);
        }
    }
}

__global__ __launch_bounds__(64) void fc2_kernel(
    const float* __restrict__ z, const float* __restrict__ W,
    const float* __restrict__ b, float* __restrict__ out)
{
    int m = blockIdx.x;
    int lane = threadIdx.x;
    float zr[8];
#pragma unroll
    for (int u = 0; u < 8; ++u) zr[u] = z[m * 512 + u * 64 + lane];
#pragma unroll
    for (int o = 0; o < 8; ++o) {
        float s = 0.f;
#pragma unroll
        for (int u = 0; u < 8; ++u) s += zr[u] * W[o * 512 + u * 64 + lane];
#pragma unroll
        for (int off = 32; off > 0; off >>= 1) s += __shfl_down(s, off);
        if (lane == 0) out[m * 8 + o] = s + b[o];
    }
}

__global__ __launch_bounds__(256) void zero_f_kernel(float* p, int n)
{
    int i = blockIdx.x * 256 + threadIdx.x;
    if (i < n) p[i] = 0.f;
}

// fp32 LSTM step for fallback path
__global__ __launch_bounds__(256) void gemm_lstm_f32(
    const float* __restrict__ A1, int lda1, int K1, const float* __restrict__ W1,
    const float* __restrict__ A2, int K2, const float* __restrict__ W2,
    const float* __restrict__ b1, const float* __restrict__ b2,
    const float* __restrict__ c_in, float* __restrict__ c_out,
    float* __restrict__ h_out)
{
    __shared__ float sA[16][33];
    __shared__ float sW[128][33];

    const int tid = threadIdx.x;
    const int tj  = tid & 31;
    const int tg  = tid >> 5;
    const int m0  = blockIdx.x * 16;
    const int j0  = blockIdx.y * 32;

    float acc[2][4] = {{0.f, 0.f, 0.f, 0.f}, {0.f, 0.f, 0.f, 0.f}};

    for (int seg = 0; seg < 2; ++seg) {
        const float* A  = seg ? A2 : A1;
        const float* W  = seg ? W2 : W1;
        const int    K  = seg ? K2 : K1;
        const int    ld = seg ? HH : lda1;
        for (int kb = 0; kb < K; kb += 32) {
            __syncthreads();
            {
                int idxq = tid;
#pragma unroll
                for (int r = 0; r < 2; ++r, idxq += 256) {
                    int row = idxq >> 5, col = idxq & 31;
                    sA[row][col] = A[(m0 + row) * ld + kb + col];
                }
            }
            {
#pragma unroll
                for (int i = 0; i < 16; ++i) {
                    int idxq = i * 256 + tid;
                    int row = idxq >> 5, col = idxq & 31;
                    int grw = (row >> 5) * HH + j0 + (row & 31);
                    sW[row][col] = W[grw * K + kb + col];
                }
            }
            __syncthreads();
#pragma unroll
            for (int k = 0; k < 32; ++k) {
                float a0 = sA[tg][k];
                float a1 = sA[tg + 8][k];
                float w0 = sW[tj][k];
                float w1 = sW[32 + tj][k];
                float w2 = sW[64 + tj][k];
                float w3 = sW[96 + tj][k];
                acc[0][0] += a0 * w0; acc[0][1] += a0 * w1;
                acc[0][2] += a0 * w2; acc[0][3] += a0 * w3;
                acc[1][0] += a1 * w0; acc[1][1] += a1 * w1;
                acc[1][2] += a1 * w2; acc[1][3] += a1 * w3;
            }
        }
    }

    const int j = j0 + tj;
    const float bi = b1[j] + b2[j];
    const float bf = b1[HH + j] + b2[HH + j];
    const float bg = b1[2 * HH + j] + b2[2 * HH + j];
    const float bo = b1[3 * HH + j] + b2[3 * HH + j];
#pragma unroll
    for (int r = 0; r < 2; ++r) {
        int m = m0 + tg + r * 8;
        float gi = acc[r][0] + bi;
        float gf = acc[r][1] + bf;
        float gg = acc[r][2] + bg;
        float go = acc[r][3] + bo;
        float cp = c_in[m * HH + j];
        float c  = sigm(gf) * cp + sigm(gi) * tanhf(gg);
        float h  = sigm(go) * tanhf(c);
        c_out[m * HH + j] = c;
        h_out[m * HH + j] = h;
    }
}

// ---------------- host ----------------

extern "C" void kernel_launch(void* const* d_in, const int* in_sizes, int n_in,
                              void* d_out, int out_size, void* d_ws, size_t ws_size,
                              hipStream_t stream)
{
    const float* x     = (const float*)d_in[0];
    const float* W_ih0 = (const float*)d_in[1];
    const float* W_hh0 = (const float*)d_in[2];
    const float* b_ih0 = (const float*)d_in[3];
    const float* b_hh0 = (const float*)d_in[4];
    const float* W_ih1 = (const float*)d_in[5];
    const float* W_hh1 = (const float*)d_in[6];
    const float* b_ih1 = (const float*)d_in[7];
    const float* b_hh1 = (const float*)d_in[8];
    const float* W_fc1 = (const float*)d_in[9];
    const float* b_fc1 = (const float*)d_in[10];
    const float* W_fc2 = (const float*)d_in[11];
    const float* b_fc2 = (const float*)d_in[12];
    float* out = (float*)d_out;

    const size_t S  = (size_t)BB * HH;        // 131072 elems
    const size_t SB = S * sizeof(u16);        // 262144 B
    const size_t SF = S * sizeof(float);      // 524288 B
    const size_t XN = (size_t)BB * TLEN * DD; // 8388608 elems
    const size_t FLAGB = (8192 + 32) * 4;

    const size_t NEED = FLAGB + 8 * SB + 2 * SF + 2 * XN * 2 +
                        2 * 131072 * 2 + 6 * 1048576 * 2;

    if (ws_size >= NEED) {
        char* W = (char*)d_ws;
        size_t o = 0;
        unsigned* flags = (unsigned*)(W + o); o += FLAGB;
        u16* h0hi0 = (u16*)(W + o); o += SB;
        u16* h0lo0 = (u16*)(W + o); o += SB;
        u16* h1hi1 = (u16*)(W + o); o += SB;
        u16* h1lo1 = (u16*)(W + o); o += SB;
        const size_t ZBYTES = o;
        u16* h0hi1 = (u16*)(W + o); o += SB;
        u16* h0lo1 = (u16*)(W + o); o += SB;
        u16* h1hi0 = (u16*)(W + o); o += SB;
        u16* h1lo0 = (u16*)(W + o); o += SB;
        float* h1last = (float*)(W + o); o += SF;
        float* zfc    = (float*)(W + o); o += SF;
        u16* xTh = (u16*)(W + o); o += XN * 2;
        u16* xTl = (u16*)(W + o); o += XN * 2;
        u16* wih0h = (u16*)(W + o); o += 131072 * 2;
        u16* wih0l = (u16*)(W + o); o += 131072 * 2;
        u16* whh0h = (u16*)(W + o); o += 1048576 * 2;
        u16* whh0l = (u16*)(W + o); o += 1048576 * 2;
        u16* wih1h = (u16*)(W + o); o += 1048576 * 2;
        u16* wih1l = (u16*)(W + o); o += 1048576 * 2;
        u16* whh1h = (u16*)(W + o); o += 1048576 * 2;
        u16* whh1l = (u16*)(W + o); o += 1048576 * 2;

        zero_kernel<<<(int)((ZBYTES / 4 + 255) / 256), 256, 0, stream>>>((unsigned*)d_ws, (int)(ZBYTES / 4));
        txpose_kernel<<<2048, 256, 0, stream>>>(x, xTh, xTl);
        split_kernel<<<512, 256, 0, stream>>>(W_ih0, wih0h, wih0l, 131072);
        split_kernel<<<2048, 256, 0, stream>>>(W_hh0, whh0h, whh0l, 1048576);
        split_kernel<<<2048, 256, 0, stream>>>(W_ih1, wih1h, wih1l, 1048576);
        split_kernel<<<2048, 256, 0, stream>>>(W_hh1, whh1h, whh1l, 1048576);

        lstm_persist<<<256, 512, 0, stream>>>(
            xTh, xTl,
            wih0h, wih0l, whh0h, whh0l,
            wih1h, wih1l, whh1h, whh1l,
            b_ih0, b_hh0, b_ih1, b_hh1,
            h0hi0, h0lo0, h0hi1, h0lo1,
            h1hi0, h1lo0, h1hi1, h1lo1,
            h1last, flags);

        dim3 grid_fc1(BB / 16, 512 / 128);
        gemm_step<1><<<grid_fc1, 256, 0, stream>>>(h1last, HH, HH, W_fc1, b_fc1, zfc);
        fc2_kernel<<<BB, 64, 0, stream>>>(zfc, W_fc2, b_fc2, out);
        return;
    }

    // -------- fallback: fp32 path --------
    float* wsf = (float*)d_ws;
    float* h0a = wsf + 0 * S;
    float* c0  = wsf + 1 * S;
    float* h1a = wsf + 2 * S;
    float* c1  = wsf + 3 * S;
    float* h0b = wsf + 4 * S;
    float* h1b = wsf + 5 * S;
    float* zb  = wsf + 6 * S;
    float* h0buf[2] = {h0a, h0b};
    float* h1buf[2] = {h1a, h1b};

    zero_f_kernel<<<(int)((4 * S + 255) / 256), 256, 0, stream>>>(wsf, (int)(4 * S));

    dim3 grid_lstm(BB / 16, HH / 32);
    for (int t = 0; t < TLEN; ++t) {
        const float* xt = x + (size_t)t * DD;
        gemm_lstm_f32<<<grid_lstm, 256, 0, stream>>>(
            xt, TLEN * DD, DD, W_ih0,
            h0buf[t & 1], HH, W_hh0,
            b_ih0, b_hh0, c0, c0, h0buf[(t + 1) & 1]);
        gemm_lstm_f32<<<grid_lstm, 256, 0, stream>>>(
            h0buf[(t + 1) & 1], HH, HH, W_ih1,
            h1buf[t & 1], HH, W_hh1,
            b_ih1, b_hh1, c1, c1, h1buf[(t + 1) & 1]);
    }
    dim3 grid_fc1(BB / 16, 512 / 128);
    gemm_step<1><<<grid_fc1, 256, 0, stream>>>(h1buf[0], HH, HH, W_fc1, b_fc1, zb);
    fc2_kernel<<<BB, 64, 0, stream>>>(zb, W_fc2, b_fc2, out);
}